// Round 7
// baseline (508.147 us; speedup 1.0000x reference)
//
#include <hip/hip_runtime.h>
#include <hip/hip_bf16.h>

typedef __attribute__((ext_vector_type(4))) float  f32x4;
typedef __attribute__((ext_vector_type(4))) float  float4v;
typedef __attribute__((ext_vector_type(8))) short  bf16x8;
typedef __attribute__((ext_vector_type(4))) short  bf16x4;
typedef __attribute__((ext_vector_type(2))) unsigned int u32x2;

#define BZ   32
#define SLEN 1024
#define TLEN 1024
#define DIM  512
#define TILE 128

// v_perm selector: out = [hi16(src0_arg) : hi16(src1_arg)]
#define PSEL 0x07060302u

__device__ __forceinline__ unsigned int fbits(float x) { return __builtin_bit_cast(unsigned int, x); }
__device__ __forceinline__ float fval(unsigned int u) { return __builtin_bit_cast(float, u); }

__device__ __forceinline__ unsigned short f2bf(float x) {   // RNE (off hot path)
  unsigned int u = fbits(x);
  unsigned int r = u + 0x7FFFu + ((u >> 16) & 1u);
  return (unsigned short)(r >> 16);
}
__device__ __forceinline__ float bf2f(unsigned short h) { return fval(((unsigned int)h) << 16); }

// pack trunc-bf16 of (x0,x1) -> u32 [bf(x1)<<16 | bf(x0)]
__device__ __forceinline__ unsigned int packhi(float x0, float x1) {
  return __builtin_amdgcn_perm(fbits(x1), fbits(x0), PSEL);
}

// 8 f32 -> hi/lo trunc-split bf16x8 fragments (exact residual: Sterbenz)
__device__ __forceinline__ void cvt8(const float4v& x0, const float4v& x1,
                                     bf16x8& hi, bf16x8& lo) {
  union { unsigned int u[4]; bf16x8 v; } H, L;
  H.u[0] = packhi(x0[0], x0[1]); H.u[1] = packhi(x0[2], x0[3]);
  H.u[2] = packhi(x1[0], x1[1]); H.u[3] = packhi(x1[2], x1[3]);
  float r0 = x0[0] - fval(fbits(x0[0]) & 0xFFFF0000u);
  float r1 = x0[1] - fval(fbits(x0[1]) & 0xFFFF0000u);
  float r2 = x0[2] - fval(fbits(x0[2]) & 0xFFFF0000u);
  float r3 = x0[3] - fval(fbits(x0[3]) & 0xFFFF0000u);
  float r4 = x1[0] - fval(fbits(x1[0]) & 0xFFFF0000u);
  float r5 = x1[1] - fval(fbits(x1[1]) & 0xFFFF0000u);
  float r6 = x1[2] - fval(fbits(x1[2]) & 0xFFFF0000u);
  float r7 = x1[3] - fval(fbits(x1[3]) & 0xFFFF0000u);
  L.u[0] = packhi(r0, r1); L.u[1] = packhi(r2, r3);
  L.u[2] = packhi(r4, r5); L.u[3] = packhi(r6, r7);
  hi = H.v; lo = L.v;
}
// 8 f32 -> trunc-bf16 hi only
__device__ __forceinline__ bf16x8 cvt8hi(const float4v& x0, const float4v& x1) {
  union { unsigned int u[4]; bf16x8 v; } H;
  H.u[0] = packhi(x0[0], x0[1]); H.u[1] = packhi(x0[2], x0[3]);
  H.u[2] = packhi(x1[0], x1[1]); H.u[3] = packhi(x1[2], x1[3]);
  return H.v;
}

// src_lengths may land as int64 or int32; values are in [1,1024] so in the
// int64 layout every odd 32-bit word is 0, while int32 layout has p[1]>=1.
__device__ __forceinline__ int get_len(const int* __restrict__ p, int b) {
  bool is64 = (p[1] == 0) && (p[3] == 0) && (p[5] == 0);
  return is64 ? p[2 * b] : p[b];
}

// ---------------------------------------------------------------- K0: src -> srcT (bf16)
#define TLP 68
__global__ __launch_bounds__(256) void k_transpose(
    const float* __restrict__ src, unsigned short* __restrict__ srcT) {
  const int b  = blockIdx.z;
  const int s0 = blockIdx.x * 64;
  const int d0 = blockIdx.y * 64;
  __shared__ unsigned short tl[64 * TLP];
  const int tid = threadIdx.x;
#pragma unroll
  for (int r = 0; r < 4; ++r) {
    const int idx = tid + 256 * r;
    const int row = idx >> 4, c4 = idx & 15;   // row: s, c4: d/4
    float4v x = *(const float4v*)(src + ((size_t)(b * SLEN + s0 + row)) * DIM + d0 + c4 * 4);
    unsigned short* pp = tl + row * TLP + c4 * 4;
    pp[0] = f2bf(x[0]); pp[1] = f2bf(x[1]); pp[2] = f2bf(x[2]); pp[3] = f2bf(x[3]);
  }
  __syncthreads();
#pragma unroll
  for (int r = 0; r < 2; ++r) {
    const int idx  = tid + 256 * r;
    const int drow = idx >> 3, c8 = idx & 7;   // drow: d, c8: s/8
    union { unsigned short u[8]; bf16x8 v; } pk;
#pragma unroll
    for (int j = 0; j < 8; ++j) pk.u[j] = tl[(c8 * 8 + j) * TLP + drow];
    *(bf16x8*)(srcT + ((size_t)(b * DIM + d0 + drow)) * SLEN + s0 + c8 * 8) = pk.v;
  }
}

// ---------------------------------------------------------------- prep: w_out -> bf16 (RNE)
__global__ __launch_bounds__(256) void k_prep_w(
    const float* __restrict__ w, unsigned short* __restrict__ wbf) {
  const size_t i = ((size_t)blockIdx.x * 256 + threadIdx.x) * 8;
  float4v x0 = *(const float4v*)(w + i);
  float4v x1 = *(const float4v*)(w + i + 4);
  union { unsigned short u[8]; bf16x8 v; } hi;
#pragma unroll
  for (int j = 0; j < 4; ++j) { hi.u[j] = f2bf(x0[j]); hi.u[4 + j] = f2bf(x1[j]); }
  *(bf16x8*)(wbf + i) = hi.v;
}

// ---------------------------------------------------------------- K1: score = tgt @ src^T (3xbf16, trunc-split)
// LDS-free direct-fragment GEMM: each lane loads its MFMA fragment straight
// from global (lane r16 = row, g*8.. = k cols), converts in-register. No
// barriers, no ds traffic -> compiler pipelines the whole K-loop.
__global__ __launch_bounds__(256) void k_score(
    const float* __restrict__ tgt, const float* __restrict__ src,
    const int* __restrict__ lens, float* __restrict__ align_out) {
  const int b  = blockIdx.z;
  const int t0 = blockIdx.x * TILE;
  const int s0 = blockIdx.y * TILE;
  const int len = get_len(lens, b);
  if (s0 >= len) return;   // fully-masked tile: softmax writes the zeros

  const int tid  = threadIdx.x;
  const int lane = tid & 63;
  const int wid  = tid >> 6;
  const int wt   = wid >> 1, wsd = wid & 1;    // 2x2 waves, 64x64 each
  const int g    = lane >> 4, r16 = lane & 15;

  f32x4 acc[4][4];
#pragma unroll
  for (int m = 0; m < 4; ++m)
#pragma unroll
    for (int n = 0; n < 4; ++n) acc[m][n] = (f32x4){0.f, 0.f, 0.f, 0.f};

  // per-lane fragment base rows
  const float* aB = tgt + ((size_t)(b * TLEN + t0 + wt * 64 + r16)) * DIM + g * 8;
  const float* bB = src + ((size_t)(b * SLEN + s0 + wsd * 64 + r16)) * DIM + g * 8;

  for (int k0 = 0; k0 < DIM; k0 += 32) {
    float4v la[4][2], lb[4][2];
#pragma unroll
    for (int m = 0; m < 4; ++m) {
      const float* p = aB + (size_t)(m * 16) * DIM + k0;
      la[m][0] = *(const float4v*)(p);
      la[m][1] = *(const float4v*)(p + 4);
    }
#pragma unroll
    for (int n = 0; n < 4; ++n) {
      const float* p = bB + (size_t)(n * 16) * DIM + k0;
      lb[n][0] = *(const float4v*)(p);
      lb[n][1] = *(const float4v*)(p + 4);
    }
    bf16x8 fah[4], fal[4], fbh[4], fbl[4];
#pragma unroll
    for (int m = 0; m < 4; ++m) cvt8(la[m][0], la[m][1], fah[m], fal[m]);
#pragma unroll
    for (int n = 0; n < 4; ++n) cvt8(lb[n][0], lb[n][1], fbh[n], fbl[n]);
#pragma unroll
    for (int m = 0; m < 4; ++m)
#pragma unroll
      for (int n = 0; n < 4; ++n) {
        acc[m][n] = __builtin_amdgcn_mfma_f32_16x16x32_bf16(fah[m], fbh[n], acc[m][n], 0, 0, 0);
        acc[m][n] = __builtin_amdgcn_mfma_f32_16x16x32_bf16(fal[m], fbh[n], acc[m][n], 0, 0, 0);
        acc[m][n] = __builtin_amdgcn_mfma_f32_16x16x32_bf16(fah[m], fbl[n], acc[m][n], 0, 0, 0);
      }
  }
  float* outB = align_out + ((size_t)(b * TLEN + t0)) * SLEN + s0;
#pragma unroll
  for (int m = 0; m < 4; ++m) {
    const int tr = wt * 64 + m * 16 + g * 4;
#pragma unroll
    for (int n = 0; n < 4; ++n) {
      const int sc = wsd * 64 + n * 16 + r16;
#pragma unroll
      for (int r = 0; r < 4; ++r)
        outB[(size_t)(tr + r) * SLEN + sc] = acc[m][n][r];
    }
  }
}

// ---------------------------------------------------------------- K2: masked softmax (in-place)
__global__ __launch_bounds__(256) void k_softmax(
    const int* __restrict__ lens, float* __restrict__ align_io) {
  const int row  = blockIdx.x * 4 + (threadIdx.x >> 6);  // b*1024 + t
  const int lane = threadIdx.x & 63;
  const int b    = row >> 10;
  const int len  = get_len(lens, b);
  float* p = align_io + (size_t)row * SLEN;
  float v[4][4];
  float mx = -3.0e38f;
#pragma unroll
  for (int q = 0; q < 4; ++q) {
    if (256 * q >= len) {
#pragma unroll
      for (int j = 0; j < 4; ++j) v[q][j] = 0.f;
      continue;
    }
    const int sb = (lane + 64 * q) * 4;
    float4v x = *(const float4v*)(p + sb);
#pragma unroll
    for (int j = 0; j < 4; ++j) {
      v[q][j] = (sb + j < len) ? x[j] : 0.f;
      if (sb + j < len) mx = fmaxf(mx, x[j]);
    }
  }
#pragma unroll
  for (int off = 1; off < 64; off <<= 1) mx = fmaxf(mx, __shfl_xor(mx, off));
  float sum = 0.f;
#pragma unroll
  for (int q = 0; q < 4; ++q) {
    const int sb = (lane + 64 * q) * 4;
#pragma unroll
    for (int j = 0; j < 4; ++j) {
      float e = (sb + j < len) ? __expf(v[q][j] - mx) : 0.f;
      v[q][j] = e; sum += e;
    }
  }
#pragma unroll
  for (int off = 1; off < 64; off <<= 1) sum += __shfl_xor(sum, off);
  const float inv = 1.f / sum;
#pragma unroll
  for (int q = 0; q < 4; ++q) {
    float4v x;
#pragma unroll
    for (int j = 0; j < 4; ++j) x[j] = v[q][j] * inv;
    *(float4v*)(p + (lane + 64 * q) * 4) = x;
  }
}

// ---------------------------------------------------------------- K3: c = align @ src (direct-frag, K clamped)
__global__ __launch_bounds__(256) void k_pv(
    const float* __restrict__ align_in, const unsigned short* __restrict__ srcT,
    const int* __restrict__ lens, unsigned short* __restrict__ cws) {
  const int b  = blockIdx.z;
  const int t0 = blockIdx.x * TILE;
  const int d0 = blockIdx.y * TILE;
  const int len = get_len(lens, b);
  const int ksteps = (len + 31) >> 5;

  const int tid  = threadIdx.x;
  const int lane = tid & 63;
  const int wid  = tid >> 6;
  const int wt   = wid >> 1, wsd = wid & 1;
  const int g    = lane >> 4, r16 = lane & 15;

  f32x4 acc[4][4];
#pragma unroll
  for (int m = 0; m < 4; ++m)
#pragma unroll
    for (int n = 0; n < 4; ++n) acc[m][n] = (f32x4){0.f, 0.f, 0.f, 0.f};

  const float*          aB = align_in + ((size_t)(b * TLEN + t0 + wt * 64 + r16)) * SLEN + g * 8;
  const unsigned short* bB = srcT     + ((size_t)(b * DIM  + d0 + wsd * 64 + r16)) * SLEN + g * 8;

  for (int ks = 0; ks < ksteps; ++ks) {
    const int k0 = ks * 32;
    bf16x8 fa[4], fb[4];
#pragma unroll
    for (int m = 0; m < 4; ++m) {
      const float* p = aB + (size_t)(m * 16) * SLEN + k0;
      float4v x0 = *(const float4v*)(p);
      float4v x1 = *(const float4v*)(p + 4);
      fa[m] = cvt8hi(x0, x1);    // align in [0,1]: trunc-bf16 fine
    }
#pragma unroll
    for (int n = 0; n < 4; ++n)
      fb[n] = *(const bf16x8*)(bB + (size_t)(n * 16) * SLEN + k0);
#pragma unroll
    for (int m = 0; m < 4; ++m)
#pragma unroll
      for (int n = 0; n < 4; ++n)
        acc[m][n] = __builtin_amdgcn_mfma_f32_16x16x32_bf16(fa[m], fb[n], acc[m][n], 0, 0, 0);
  }
#pragma unroll
  for (int m = 0; m < 4; ++m) {
    const int tr = wt * 64 + m * 16 + g * 4;
#pragma unroll
    for (int n = 0; n < 4; ++n) {
      const int dc = wsd * 64 + n * 16 + r16;
#pragma unroll
      for (int r = 0; r < 4; ++r)
        cws[((size_t)(b * TLEN + t0 + tr + r)) * DIM + d0 + dc] = f2bf(acc[m][n][r]);
    }
  }
}

// ---------------------------------------------------------------- K4: attn_h = [c,tgt] @ w_out^T (direct-frag)
__global__ __launch_bounds__(256) void k_proj(
    const unsigned short* __restrict__ cws, const float* __restrict__ tgt,
    const unsigned short* __restrict__ wbf, float* __restrict__ attn_out) {
  const int b  = blockIdx.z;
  const int t0 = blockIdx.x * TILE;
  const int d0 = blockIdx.y * TILE;

  const int tid  = threadIdx.x;
  const int lane = tid & 63;
  const int wid  = tid >> 6;
  const int wt   = wid >> 1, wsd = wid & 1;
  const int g    = lane >> 4, r16 = lane & 15;

  f32x4 acc[4][4];
#pragma unroll
  for (int m = 0; m < 4; ++m)
#pragma unroll
    for (int n = 0; n < 4; ++n) acc[m][n] = (f32x4){0.f, 0.f, 0.f, 0.f};

  const unsigned short* cB = cws + ((size_t)(b * TLEN + t0 + wt * 64 + r16)) * DIM + g * 8;
  const float*          tB = tgt + ((size_t)(b * TLEN + t0 + wt * 64 + r16)) * DIM + g * 8;
  const unsigned short* wB = wbf + ((size_t)(d0 + wsd * 64 + r16)) * (2 * DIM) + g * 8;

  for (int k0 = 0; k0 < 2 * DIM; k0 += 32) {
    bf16x8 fa[4], fb[4];
    if (k0 < DIM) {
#pragma unroll
      for (int m = 0; m < 4; ++m)
        fa[m] = *(const bf16x8*)(cB + (size_t)(m * 16) * DIM + k0);
    } else {
#pragma unroll
      for (int m = 0; m < 4; ++m) {
        const float* p = tB + (size_t)(m * 16) * DIM + (k0 - DIM);
        float4v x0 = *(const float4v*)(p);
        float4v x1 = *(const float4v*)(p + 4);
        fa[m] = cvt8hi(x0, x1);
      }
    }
#pragma unroll
    for (int n = 0; n < 4; ++n)
      fb[n] = *(const bf16x8*)(wB + (size_t)(n * 16) * (2 * DIM) + k0);
#pragma unroll
    for (int m = 0; m < 4; ++m)
#pragma unroll
      for (int n = 0; n < 4; ++n)
        acc[m][n] = __builtin_amdgcn_mfma_f32_16x16x32_bf16(fa[m], fb[n], acc[m][n], 0, 0, 0);
  }
#pragma unroll
  for (int m = 0; m < 4; ++m) {
    const int tr = wt * 64 + m * 16 + g * 4;
#pragma unroll
    for (int n = 0; n < 4; ++n) {
      const int dc = wsd * 64 + n * 16 + r16;
#pragma unroll
      for (int r = 0; r < 4; ++r)
        attn_out[((size_t)(b * TLEN + t0 + tr + r)) * DIM + d0 + dc] = acc[m][n][r];
    }
  }
}

extern "C" void kernel_launch(void* const* d_in, const int* in_sizes, int n_in,
                              void* d_out, int out_size, void* d_ws, size_t ws_size,
                              hipStream_t stream) {
  const float* src   = (const float*)d_in[0];
  const float* tgt   = (const float*)d_in[1];
  const int*   lens  = (const int*)d_in[2];
  const float* w_out = (const float*)d_in[3];

  float* attn_out  = (float*)d_out;                          // 32*1024*512 f32
  float* align_out = attn_out + (size_t)BZ * TLEN * DIM;     // 32*1024*1024 f32

  const size_t NE = (size_t)BZ * SLEN * DIM;
  const size_t NW = (size_t)DIM * 2 * DIM;
  unsigned short* srcT = (unsigned short*)d_ws;
  unsigned short* cws  = srcT + NE;
  unsigned short* wbf  = cws + NE;

  k_transpose<<<dim3(16, 8, BZ), 256, 0, stream>>>(src, srcT);
  k_prep_w<<<dim3((unsigned)(NW / 8 / 256)), 256, 0, stream>>>(w_out, wbf);
  k_score<<<dim3(8, 8, BZ), 256, 0, stream>>>(tgt, src, lens, align_out);
  k_softmax<<<dim3(BZ * TLEN / 4), 256, 0, stream>>>(lens, align_out);
  k_pv<<<dim3(8, 4, BZ), 256, 0, stream>>>(align_out, srcT, lens, cws);
  k_proj<<<dim3(8, 4, BZ), 256, 0, stream>>>(cws, tgt, wbf, attn_out);
}

// Round 8
// 282.644 us; speedup vs baseline: 1.7978x; 1.7978x over previous
//
#include <hip/hip_runtime.h>
#include <hip/hip_bf16.h>

typedef __attribute__((ext_vector_type(4))) float  f32x4;
typedef __attribute__((ext_vector_type(4))) float  float4v;
typedef __attribute__((ext_vector_type(8))) short  bf16x8;
typedef __attribute__((ext_vector_type(4))) short  bf16x4;
typedef __attribute__((ext_vector_type(2))) unsigned int u32x2;

#define BZ   32
#define SLEN 1024
#define TLEN 1024
#define DIM  512
#define TILE 128
#define LP   64   // LDS row pitch (shorts): 128B rows, XOR-swizzled 16B slots

// v_perm selector: out = [hi16(src0_arg) : hi16(src1_arg)]
#define PSEL 0x07060302u

__device__ __forceinline__ unsigned int fbits(float x) { return __builtin_bit_cast(unsigned int, x); }
__device__ __forceinline__ float fval(unsigned int u) { return __builtin_bit_cast(float, u); }

__device__ __forceinline__ unsigned short f2bf(float x) {   // RNE (off hot path)
  unsigned int u = fbits(x);
  unsigned int r = u + 0x7FFFu + ((u >> 16) & 1u);
  return (unsigned short)(r >> 16);
}
__device__ __forceinline__ float bf2f(unsigned short h) { return fval(((unsigned int)h) << 16); }

// pack trunc-bf16 of (x0,x1) -> u32 [bf(x1)<<16 | bf(x0)]
__device__ __forceinline__ unsigned int packhi(float x0, float x1) {
  return __builtin_amdgcn_perm(fbits(x1), fbits(x0), PSEL);
}

// swizzled short-offset helpers. slot = 8 shorts (16B). phys_slot = slot ^ (row&7)
__device__ __forceinline__ int swz8(int row, int slot) {         // full-slot (16B) unit
  return row * LP + ((slot ^ (row & 7)) << 3);
}
__device__ __forceinline__ int swz4(int row, int c4) {           // 8B unit (c4 = 0..7 half-slots)
  return row * LP + (((c4 >> 1) ^ (row & 7)) << 3) + ((c4 & 1) << 2);
}

// src_lengths may land as int64 or int32; values are in [1,1024] so in the
// int64 layout every odd 32-bit word is 0, while int32 layout has p[1]>=1.
__device__ __forceinline__ int get_len(const int* __restrict__ p, int b) {
  bool is64 = (p[1] == 0) && (p[3] == 0) && (p[5] == 0);
  return is64 ? p[2 * b] : p[b];
}

// ---------------------------------------------------------------- K0: src -> srcT (bf16)
#define TLP 68
__global__ __launch_bounds__(256) void k_transpose(
    const float* __restrict__ src, unsigned short* __restrict__ srcT) {
  const int b  = blockIdx.z;
  const int s0 = blockIdx.x * 64;
  const int d0 = blockIdx.y * 64;
  __shared__ unsigned short tl[64 * TLP];
  const int tid = threadIdx.x;
#pragma unroll
  for (int r = 0; r < 4; ++r) {
    const int idx = tid + 256 * r;
    const int row = idx >> 4, c4 = idx & 15;   // row: s, c4: d/4
    float4v x = *(const float4v*)(src + ((size_t)(b * SLEN + s0 + row)) * DIM + d0 + c4 * 4);
    unsigned short* pp = tl + row * TLP + c4 * 4;
    pp[0] = f2bf(x[0]); pp[1] = f2bf(x[1]); pp[2] = f2bf(x[2]); pp[3] = f2bf(x[3]);
  }
  __syncthreads();
#pragma unroll
  for (int r = 0; r < 2; ++r) {
    const int idx  = tid + 256 * r;
    const int drow = idx >> 3, c8 = idx & 7;   // drow: d, c8: s/8
    union { unsigned short u[8]; bf16x8 v; } pk;
#pragma unroll
    for (int j = 0; j < 8; ++j) pk.u[j] = tl[(c8 * 8 + j) * TLP + drow];
    *(bf16x8*)(srcT + ((size_t)(b * DIM + d0 + drow)) * SLEN + s0 + c8 * 8) = pk.v;
  }
}

// ---------------------------------------------------------------- prep: w_out -> bf16 (RNE)
__global__ __launch_bounds__(256) void k_prep_w(
    const float* __restrict__ w, unsigned short* __restrict__ wbf) {
  const size_t i = ((size_t)blockIdx.x * 256 + threadIdx.x) * 8;
  float4v x0 = *(const float4v*)(w + i);
  float4v x1 = *(const float4v*)(w + i + 4);
  union { unsigned short u[8]; bf16x8 v; } hi;
#pragma unroll
  for (int j = 0; j < 4; ++j) { hi.u[j] = f2bf(x0[j]); hi.u[4 + j] = f2bf(x1[j]); }
  *(bf16x8*)(wbf + i) = hi.v;
}

// ---------------------------------------------------------------- K1: score = tgt @ src^T (3xbf16, trunc-split)
// Register-prefetch pipeline + XOR-swizzled LDS (conflict-free frag reads).
__global__ __launch_bounds__(256) void k_score(
    const float* __restrict__ tgt, const float* __restrict__ src,
    const int* __restrict__ lens, float* __restrict__ align_out) {
  const int b  = blockIdx.z;
  const int t0 = blockIdx.x * TILE;
  const int s0 = blockIdx.y * TILE;
  const int len = get_len(lens, b);
  if (s0 >= len) return;   // fully-masked tile: softmax writes the zeros

  __shared__ short aHi[TILE * LP], aLo[TILE * LP], bHi[TILE * LP], bLo[TILE * LP];

  const int tid  = threadIdx.x;
  const int lane = tid & 63;
  const int wid  = tid >> 6;
  const int wt   = wid >> 1, wsd = wid & 1;    // 2x2 waves, 64x64 each
  const int g    = lane >> 4, r16 = lane & 15;
  const int srow = tid >> 3, sc4 = tid & 7;

  f32x4 acc[4][4];
#pragma unroll
  for (int m = 0; m < 4; ++m)
#pragma unroll
    for (int n = 0; n < 4; ++n) acc[m][n] = (f32x4){0.f, 0.f, 0.f, 0.f};

  const float* tgtB = tgt + ((size_t)(b * TLEN + t0)) * DIM;
  const float* srcB = src + ((size_t)(b * SLEN + s0)) * DIM;

  float4v va[4], vb[4];
#pragma unroll
  for (int r = 0; r < 4; ++r) {   // prologue: prefetch k0 = 0
    const int row = srow + 32 * r;
    va[r] = *(const float4v*)(tgtB + (size_t)row * DIM + sc4 * 4);
    vb[r] = *(const float4v*)(srcB + (size_t)row * DIM + sc4 * 4);
  }

  for (int k0 = 0; k0 < DIM; k0 += 32) {
    // phase 1: convert current regs -> LDS (vmcnt wait on prefetch lands here)
#pragma unroll
    for (int r = 0; r < 4; ++r) {
      const int row = srow + 32 * r;
      u32x2 ah, al, bh, bl;
      ah[0] = packhi(va[r][0], va[r][1]); ah[1] = packhi(va[r][2], va[r][3]);
      bh[0] = packhi(vb[r][0], vb[r][1]); bh[1] = packhi(vb[r][2], vb[r][3]);
      float ra0 = va[r][0] - fval(fbits(va[r][0]) & 0xFFFF0000u);
      float ra1 = va[r][1] - fval(fbits(va[r][1]) & 0xFFFF0000u);
      float ra2 = va[r][2] - fval(fbits(va[r][2]) & 0xFFFF0000u);
      float ra3 = va[r][3] - fval(fbits(va[r][3]) & 0xFFFF0000u);
      float rb0 = vb[r][0] - fval(fbits(vb[r][0]) & 0xFFFF0000u);
      float rb1 = vb[r][1] - fval(fbits(vb[r][1]) & 0xFFFF0000u);
      float rb2 = vb[r][2] - fval(fbits(vb[r][2]) & 0xFFFF0000u);
      float rb3 = vb[r][3] - fval(fbits(vb[r][3]) & 0xFFFF0000u);
      al[0] = packhi(ra0, ra1); al[1] = packhi(ra2, ra3);
      bl[0] = packhi(rb0, rb1); bl[1] = packhi(rb2, rb3);
      const int o = swz4(row, sc4);
      *(u32x2*)(aHi + o) = ah; *(u32x2*)(aLo + o) = al;
      *(u32x2*)(bHi + o) = bh; *(u32x2*)(bLo + o) = bl;
    }
    // phase 2: issue next K-step loads (consumed after MFMA+barrier)
    if (k0 + 32 < DIM) {
#pragma unroll
      for (int r = 0; r < 4; ++r) {
        const int row = srow + 32 * r;
        va[r] = *(const float4v*)(tgtB + (size_t)row * DIM + (k0 + 32) + sc4 * 4);
        vb[r] = *(const float4v*)(srcB + (size_t)row * DIM + (k0 + 32) + sc4 * 4);
      }
    }
    __syncthreads();
    // phase 3: frags + MFMA
    bf16x8 fbh[4], fbl[4];
#pragma unroll
    for (int n = 0; n < 4; ++n) {
      const int o = swz8(wsd * 64 + n * 16 + r16, g);
      fbh[n] = *(const bf16x8*)(bHi + o);
      fbl[n] = *(const bf16x8*)(bLo + o);
    }
#pragma unroll
    for (int m = 0; m < 4; ++m) {
      const int o = swz8(wt * 64 + m * 16 + r16, g);
      bf16x8 fah = *(const bf16x8*)(aHi + o);
      bf16x8 fal = *(const bf16x8*)(aLo + o);
#pragma unroll
      for (int n = 0; n < 4; ++n) {
        acc[m][n] = __builtin_amdgcn_mfma_f32_16x16x32_bf16(fah, fbh[n], acc[m][n], 0, 0, 0);
        acc[m][n] = __builtin_amdgcn_mfma_f32_16x16x32_bf16(fal, fbh[n], acc[m][n], 0, 0, 0);
        acc[m][n] = __builtin_amdgcn_mfma_f32_16x16x32_bf16(fah, fbl[n], acc[m][n], 0, 0, 0);
      }
    }
    __syncthreads();
  }
  float* outB = align_out + ((size_t)(b * TLEN + t0)) * SLEN + s0;
#pragma unroll
  for (int m = 0; m < 4; ++m) {
    const int tr = wt * 64 + m * 16 + g * 4;
#pragma unroll
    for (int n = 0; n < 4; ++n) {
      const int sc = wsd * 64 + n * 16 + r16;
#pragma unroll
      for (int r = 0; r < 4; ++r)
        outB[(size_t)(tr + r) * SLEN + sc] = acc[m][n][r];
    }
  }
}

// ---------------------------------------------------------------- K2: masked softmax (in-place)
__global__ __launch_bounds__(256) void k_softmax(
    const int* __restrict__ lens, float* __restrict__ align_io) {
  const int row  = blockIdx.x * 4 + (threadIdx.x >> 6);  // b*1024 + t
  const int lane = threadIdx.x & 63;
  const int b    = row >> 10;
  const int len  = get_len(lens, b);
  float* p = align_io + (size_t)row * SLEN;
  float v[4][4];
  float mx = -3.0e38f;
#pragma unroll
  for (int q = 0; q < 4; ++q) {
    if (256 * q >= len) {
#pragma unroll
      for (int j = 0; j < 4; ++j) v[q][j] = 0.f;
      continue;
    }
    const int sb = (lane + 64 * q) * 4;
    float4v x = *(const float4v*)(p + sb);
#pragma unroll
    for (int j = 0; j < 4; ++j) {
      v[q][j] = (sb + j < len) ? x[j] : 0.f;
      if (sb + j < len) mx = fmaxf(mx, x[j]);
    }
  }
#pragma unroll
  for (int off = 1; off < 64; off <<= 1) mx = fmaxf(mx, __shfl_xor(mx, off));
  float sum = 0.f;
#pragma unroll
  for (int q = 0; q < 4; ++q) {
    const int sb = (lane + 64 * q) * 4;
#pragma unroll
    for (int j = 0; j < 4; ++j) {
      float e = (sb + j < len) ? __expf(v[q][j] - mx) : 0.f;
      v[q][j] = e; sum += e;
    }
  }
#pragma unroll
  for (int off = 1; off < 64; off <<= 1) sum += __shfl_xor(sum, off);
  const float inv = 1.f / sum;
#pragma unroll
  for (int q = 0; q < 4; ++q) {
    float4v x;
#pragma unroll
    for (int j = 0; j < 4; ++j) x[j] = v[q][j] * inv;
    *(float4v*)(p + (lane + 64 * q) * 4) = x;
  }
}

// ---------------------------------------------------------------- K3: c = align @ src (bf16, K clamped, prefetch, swizzled)
__global__ __launch_bounds__(256) void k_pv(
    const float* __restrict__ align_in, const unsigned short* __restrict__ srcT,
    const int* __restrict__ lens, unsigned short* __restrict__ cws) {
  const int b  = blockIdx.z;
  const int t0 = blockIdx.x * TILE;
  const int d0 = blockIdx.y * TILE;
  const int len = get_len(lens, b);
  const int ksteps = (len + 31) >> 5;

  __shared__ short A[TILE * LP], B[TILE * LP];
  const int tid  = threadIdx.x;
  const int lane = tid & 63;
  const int wid  = tid >> 6;
  const int wt   = wid >> 1, wsd = wid & 1;
  const int g    = lane >> 4, r16 = lane & 15;

  f32x4 acc[4][4];
#pragma unroll
  for (int m = 0; m < 4; ++m)
#pragma unroll
    for (int n = 0; n < 4; ++n) acc[m][n] = (f32x4){0.f, 0.f, 0.f, 0.f};

  const int arow = tid >> 3, ac4 = tid & 7;
  const int brow = tid >> 2, bc8 = tid & 3;

  float4v xa[4];
  bf16x8  xb[2];
#pragma unroll
  for (int r = 0; r < 4; ++r)
    xa[r] = *(const float4v*)(align_in + ((size_t)(b * TLEN + t0 + arow + 32 * r)) * SLEN + ac4 * 4);
#pragma unroll
  for (int r = 0; r < 2; ++r)
    xb[r] = *(const bf16x8*)(srcT + ((size_t)(b * DIM + d0 + brow + 64 * r)) * SLEN + bc8 * 8);

  for (int ks = 0; ks < ksteps; ++ks) {
#pragma unroll
    for (int r = 0; r < 4; ++r) {   // A: align rows t (trunc-bf16 ok: align in [0,1])
      u32x2 h;
      h[0] = packhi(xa[r][0], xa[r][1]); h[1] = packhi(xa[r][2], xa[r][3]);
      *(u32x2*)(A + swz4(arow + 32 * r, ac4)) = h;
    }
#pragma unroll
    for (int r = 0; r < 2; ++r)     // B: srcT rows d
      *(bf16x8*)(B + swz8(brow + 64 * r, bc8)) = xb[r];
    if (ks + 1 < ksteps) {
      const int k0 = (ks + 1) * 32;
#pragma unroll
      for (int r = 0; r < 4; ++r)
        xa[r] = *(const float4v*)(align_in + ((size_t)(b * TLEN + t0 + arow + 32 * r)) * SLEN + k0 + ac4 * 4);
#pragma unroll
      for (int r = 0; r < 2; ++r)
        xb[r] = *(const bf16x8*)(srcT + ((size_t)(b * DIM + d0 + brow + 64 * r)) * SLEN + k0 + bc8 * 8);
    }
    __syncthreads();
    bf16x8 fb[4];
#pragma unroll
    for (int n = 0; n < 4; ++n) fb[n] = *(const bf16x8*)(B + swz8(wsd * 64 + n * 16 + r16, g));
#pragma unroll
    for (int m = 0; m < 4; ++m) {
      bf16x8 fa = *(const bf16x8*)(A + swz8(wt * 64 + m * 16 + r16, g));
#pragma unroll
      for (int n = 0; n < 4; ++n)
        acc[m][n] = __builtin_amdgcn_mfma_f32_16x16x32_bf16(fa, fb[n], acc[m][n], 0, 0, 0);
    }
    __syncthreads();
  }
#pragma unroll
  for (int m = 0; m < 4; ++m) {
    const int tr = wt * 64 + m * 16 + g * 4;
#pragma unroll
    for (int n = 0; n < 4; ++n) {
      const int dc = wsd * 64 + n * 16 + r16;
#pragma unroll
      for (int r = 0; r < 4; ++r)
        cws[((size_t)(b * TLEN + t0 + tr + r)) * DIM + d0 + dc] = f2bf(acc[m][n][r]);
    }
  }
}

// ---------------------------------------------------------------- K4: attn_h = [c,tgt] @ w_out^T (bf16, swizzled)
__global__ __launch_bounds__(256) void k_proj(
    const unsigned short* __restrict__ cws, const float* __restrict__ tgt,
    const unsigned short* __restrict__ wbf, float* __restrict__ attn_out) {
  const int b  = blockIdx.z;
  const int t0 = blockIdx.x * TILE;
  const int d0 = blockIdx.y * TILE;

  __shared__ short A[TILE * LP], B[TILE * LP];
  const int tid  = threadIdx.x;
  const int lane = tid & 63;
  const int wid  = tid >> 6;
  const int wt   = wid >> 1, wsd = wid & 1;
  const int g    = lane >> 4, r16 = lane & 15;

  f32x4 acc[4][4];
#pragma unroll
  for (int m = 0; m < 4; ++m)
#pragma unroll
    for (int n = 0; n < 4; ++n) acc[m][n] = (f32x4){0.f, 0.f, 0.f, 0.f};

  for (int k0 = 0; k0 < 2 * DIM; k0 += 32) {
    if (k0 < DIM) {   // A from c (already bf16)
#pragma unroll
      for (int r = 0; r < 2; ++r) {
        const int row = (tid >> 2) + 64 * r, c8 = tid & 3;
        bf16x8 x = *(const bf16x8*)(cws + ((size_t)(b * TLEN + t0 + row)) * DIM + k0 + c8 * 8);
        *(bf16x8*)(A + swz8(row, c8)) = x;
      }
    } else {          // A from tgt (f32 -> bf16 RNE, margin for the fp32 output)
#pragma unroll
      for (int r = 0; r < 4; ++r) {
        const int row = (tid >> 3) + 32 * r, c4 = tid & 7;
        float4v x = *(const float4v*)(tgt + ((size_t)(b * TLEN + t0 + row)) * DIM + (k0 - DIM) + c4 * 4);
        bf16x4 h;
#pragma unroll
        for (int j = 0; j < 4; ++j) h[j] = (short)f2bf(x[j]);
        *(bf16x4*)(A + swz4(row, c4)) = h;
      }
    }
#pragma unroll
    for (int r = 0; r < 2; ++r) {   // B: wbf rows d, cols e (bf16 copy)
      const int row = (tid >> 2) + 64 * r, c8 = tid & 3;
      bf16x8 x = *(const bf16x8*)(wbf + ((size_t)(d0 + row)) * (2 * DIM) + k0 + c8 * 8);
      *(bf16x8*)(B + swz8(row, c8)) = x;
    }
    __syncthreads();
    bf16x8 fb[4];
#pragma unroll
    for (int n = 0; n < 4; ++n) fb[n] = *(const bf16x8*)(B + swz8(wsd * 64 + n * 16 + r16, g));
#pragma unroll
    for (int m = 0; m < 4; ++m) {
      bf16x8 fa = *(const bf16x8*)(A + swz8(wt * 64 + m * 16 + r16, g));
#pragma unroll
      for (int n = 0; n < 4; ++n)
        acc[m][n] = __builtin_amdgcn_mfma_f32_16x16x32_bf16(fa, fb[n], acc[m][n], 0, 0, 0);
    }
    __syncthreads();
  }
#pragma unroll
  for (int m = 0; m < 4; ++m) {
    const int tr = wt * 64 + m * 16 + g * 4;
#pragma unroll
    for (int n = 0; n < 4; ++n) {
      const int dc = wsd * 64 + n * 16 + r16;
#pragma unroll
      for (int r = 0; r < 4; ++r)
        attn_out[((size_t)(b * TLEN + t0 + tr + r)) * DIM + d0 + dc] = acc[m][n][r];
    }
  }
}

extern "C" void kernel_launch(void* const* d_in, const int* in_sizes, int n_in,
                              void* d_out, int out_size, void* d_ws, size_t ws_size,
                              hipStream_t stream) {
  const float* src   = (const float*)d_in[0];
  const float* tgt   = (const float*)d_in[1];
  const int*   lens  = (const int*)d_in[2];
  const float* w_out = (const float*)d_in[3];

  float* attn_out  = (float*)d_out;                          // 32*1024*512 f32
  float* align_out = attn_out + (size_t)BZ * TLEN * DIM;     // 32*1024*1024 f32

  const size_t NE = (size_t)BZ * SLEN * DIM;
  const size_t NW = (size_t)DIM * 2 * DIM;
  unsigned short* srcT = (unsigned short*)d_ws;
  unsigned short* cws  = srcT + NE;
  unsigned short* wbf  = cws + NE;

  k_transpose<<<dim3(16, 8, BZ), 256, 0, stream>>>(src, srcT);
  k_prep_w<<<dim3((unsigned)(NW / 8 / 256)), 256, 0, stream>>>(w_out, wbf);
  k_score<<<dim3(8, 8, BZ), 256, 0, stream>>>(tgt, src, lens, align_out);
  k_softmax<<<dim3(BZ * TLEN / 4), 256, 0, stream>>>(lens, align_out);
  k_pv<<<dim3(8, 4, BZ), 256, 0, stream>>>(align_out, srcT, lens, cws);
  k_proj<<<dim3(8, 4, BZ), 256, 0, stream>>>(cws, tgt, wbf, attn_out);
}

// Round 9
// 269.702 us; speedup vs baseline: 1.8841x; 1.0480x over previous
//
#include <hip/hip_runtime.h>
#include <hip/hip_bf16.h>

typedef __attribute__((ext_vector_type(4))) float  f32x4;
typedef __attribute__((ext_vector_type(4))) float  float4v;
typedef __attribute__((ext_vector_type(8))) short  bf16x8;
typedef __attribute__((ext_vector_type(4))) short  bf16x4;
typedef __attribute__((ext_vector_type(2))) unsigned int u32x2;

#define BZ   32
#define SLEN 1024
#define TLEN 1024
#define DIM  512
#define TILE 128
#define LP   40   // LDS row pitch (shorts): 80B rows (R5 best config)

// v_perm selector: out = [hi16(src0_arg) : hi16(src1_arg)]
#define PSEL 0x07060302u

__device__ __forceinline__ unsigned int fbits(float x) { return __builtin_bit_cast(unsigned int, x); }
__device__ __forceinline__ float fval(unsigned int u) { return __builtin_bit_cast(float, u); }

__device__ __forceinline__ unsigned short f2bf(float x) {   // RNE (off hot path)
  unsigned int u = fbits(x);
  unsigned int r = u + 0x7FFFu + ((u >> 16) & 1u);
  return (unsigned short)(r >> 16);
}
__device__ __forceinline__ float bf2f(unsigned short h) { return fval(((unsigned int)h) << 16); }

// pack trunc-bf16 of (x0,x1) -> u32 [bf(x1)<<16 | bf(x0)]
__device__ __forceinline__ unsigned int packhi(float x0, float x1) {
  return __builtin_amdgcn_perm(fbits(x1), fbits(x0), PSEL);
}

// src_lengths may land as int64 or int32; values are in [1,1024] so in the
// int64 layout every odd 32-bit word is 0, while int32 layout has p[1]>=1.
__device__ __forceinline__ int get_len(const int* __restrict__ p, int b) {
  bool is64 = (p[1] == 0) && (p[3] == 0) && (p[5] == 0);
  return is64 ? p[2 * b] : p[b];
}

// ---------------------------------------------------------------- K_count: sorted worklist
// meta[0..31]  = order (rank -> batch), sorted by len descending
// meta[32+r]   = prefix offs over sorted ranks, r = 0..32 (items = 8 * ceil(len/128))
__global__ __launch_bounds__(64) void k_count(
    const int* __restrict__ lens, int* __restrict__ meta) {
  __shared__ int sLen[32], sOrder[32], sNt[33];
  const int lane = threadIdx.x;
  if (lane < 32) sLen[lane] = get_len(lens, lane);
  __syncthreads();
  if (lane < 32) {
    const int li = sLen[lane];
    int rank = 0;
#pragma unroll
    for (int j = 0; j < 32; ++j) {
      const int lj = sLen[j];
      if (lj > li || (lj == li && j < lane)) ++rank;
    }
    sOrder[rank] = lane;
  }
  __syncthreads();
  if (lane < 32) {
    meta[lane] = sOrder[lane];
    sNt[lane] = ((sLen[sOrder[lane]] + 127) >> 7) * 8;
  }
  __syncthreads();
  if (lane == 0) {
    int acc = 0;
    meta[32] = 0;
    for (int r = 0; r < 32; ++r) { acc += sNt[r]; meta[33 + r] = acc; }
  }
}

// ---------------------------------------------------------------- K0: src -> srcT (bf16)
#define TLP 68
__global__ __launch_bounds__(256) void k_transpose(
    const float* __restrict__ src, unsigned short* __restrict__ srcT) {
  const int b  = blockIdx.z;
  const int s0 = blockIdx.x * 64;
  const int d0 = blockIdx.y * 64;
  __shared__ unsigned short tl[64 * TLP];
  const int tid = threadIdx.x;
#pragma unroll
  for (int r = 0; r < 4; ++r) {
    const int idx = tid + 256 * r;
    const int row = idx >> 4, c4 = idx & 15;   // row: s, c4: d/4
    float4v x = *(const float4v*)(src + ((size_t)(b * SLEN + s0 + row)) * DIM + d0 + c4 * 4);
    unsigned short* pp = tl + row * TLP + c4 * 4;
    pp[0] = f2bf(x[0]); pp[1] = f2bf(x[1]); pp[2] = f2bf(x[2]); pp[3] = f2bf(x[3]);
  }
  __syncthreads();
#pragma unroll
  for (int r = 0; r < 2; ++r) {
    const int idx  = tid + 256 * r;
    const int drow = idx >> 3, c8 = idx & 7;   // drow: d, c8: s/8
    union { unsigned short u[8]; bf16x8 v; } pk;
#pragma unroll
    for (int j = 0; j < 8; ++j) pk.u[j] = tl[(c8 * 8 + j) * TLP + drow];
    *(bf16x8*)(srcT + ((size_t)(b * DIM + d0 + drow)) * SLEN + s0 + c8 * 8) = pk.v;
  }
}

// ---------------------------------------------------------------- prep: w_out -> bf16 (RNE)
__global__ __launch_bounds__(256) void k_prep_w(
    const float* __restrict__ w, unsigned short* __restrict__ wbf) {
  const size_t i = ((size_t)blockIdx.x * 256 + threadIdx.x) * 8;
  float4v x0 = *(const float4v*)(w + i);
  float4v x1 = *(const float4v*)(w + i + 4);
  union { unsigned short u[8]; bf16x8 v; } hi;
#pragma unroll
  for (int j = 0; j < 4; ++j) { hi.u[j] = f2bf(x0[j]); hi.u[4 + j] = f2bf(x1[j]); }
  *(bf16x8*)(wbf + i) = hi.v;
}

// ---------------------------------------------------------------- K1: score = tgt @ src^T (3xbf16, trunc-split)
// Static compacted worklist (longest batch first) + reg-prefetch pipeline.
__global__ __launch_bounds__(256) void k_score(
    const float* __restrict__ tgt, const float* __restrict__ src,
    const int* __restrict__ meta, float* __restrict__ align_out) {
  __shared__ short aHi[TILE * LP], aLo[TILE * LP], bHi[TILE * LP], bLo[TILE * LP];
  __shared__ int sOrder[32], sOffs[33];

  const int tid  = threadIdx.x;
  if (tid < 32) sOrder[tid] = meta[tid];
  if (tid < 33) sOffs[tid] = meta[32 + tid];
  __syncthreads();

  const int item = blockIdx.x;
  if (item >= sOffs[32]) return;   // compacted tail: exits instantly

  int r = 0;
  while (sOffs[r + 1] <= item) ++r;
  const int b      = sOrder[r];
  const int within = item - sOffs[r];
  const int nt     = (sOffs[r + 1] - sOffs[r]) >> 3;
  const int t_idx  = within / nt;
  const int s_idx  = within - t_idx * nt;
  const int t0 = t_idx * TILE, s0 = s_idx * TILE;

  const int lane = tid & 63;
  const int wid  = tid >> 6;
  const int wt   = wid >> 1, wsd = wid & 1;    // 2x2 waves, 64x64 each
  const int g    = lane >> 4, r16 = lane & 15;
  const int srow = tid >> 3, sc4 = tid & 7;

  f32x4 acc[4][4];
#pragma unroll
  for (int m = 0; m < 4; ++m)
#pragma unroll
    for (int n = 0; n < 4; ++n) acc[m][n] = (f32x4){0.f, 0.f, 0.f, 0.f};

  const float* tgtB = tgt + ((size_t)(b * TLEN + t0)) * DIM;
  const float* srcB = src + ((size_t)(b * SLEN + s0)) * DIM;

  float4v va[4], vb[4];
#pragma unroll
  for (int r2 = 0; r2 < 4; ++r2) {   // prologue: prefetch k0 = 0
    const int row = srow + 32 * r2;
    va[r2] = *(const float4v*)(tgtB + (size_t)row * DIM + sc4 * 4);
    vb[r2] = *(const float4v*)(srcB + (size_t)row * DIM + sc4 * 4);
  }

  for (int k0 = 0; k0 < DIM; k0 += 32) {
    // phase 1: convert current regs -> LDS (vmcnt wait on prefetch lands here)
#pragma unroll
    for (int r2 = 0; r2 < 4; ++r2) {
      const int row = srow + 32 * r2;
      u32x2 ah, al, bh, bl;
      ah[0] = packhi(va[r2][0], va[r2][1]); ah[1] = packhi(va[r2][2], va[r2][3]);
      bh[0] = packhi(vb[r2][0], vb[r2][1]); bh[1] = packhi(vb[r2][2], vb[r2][3]);
      float ra0 = va[r2][0] - fval(fbits(va[r2][0]) & 0xFFFF0000u);
      float ra1 = va[r2][1] - fval(fbits(va[r2][1]) & 0xFFFF0000u);
      float ra2 = va[r2][2] - fval(fbits(va[r2][2]) & 0xFFFF0000u);
      float ra3 = va[r2][3] - fval(fbits(va[r2][3]) & 0xFFFF0000u);
      float rb0 = vb[r2][0] - fval(fbits(vb[r2][0]) & 0xFFFF0000u);
      float rb1 = vb[r2][1] - fval(fbits(vb[r2][1]) & 0xFFFF0000u);
      float rb2 = vb[r2][2] - fval(fbits(vb[r2][2]) & 0xFFFF0000u);
      float rb3 = vb[r2][3] - fval(fbits(vb[r2][3]) & 0xFFFF0000u);
      al[0] = packhi(ra0, ra1); al[1] = packhi(ra2, ra3);
      bl[0] = packhi(rb0, rb1); bl[1] = packhi(rb2, rb3);
      const int o = row * LP + sc4 * 4;
      *(u32x2*)(aHi + o) = ah; *(u32x2*)(aLo + o) = al;
      *(u32x2*)(bHi + o) = bh; *(u32x2*)(bLo + o) = bl;
    }
    // phase 2: issue next K-step loads (consumed after MFMA+barrier)
    if (k0 + 32 < DIM) {
#pragma unroll
      for (int r2 = 0; r2 < 4; ++r2) {
        const int row = srow + 32 * r2;
        va[r2] = *(const float4v*)(tgtB + (size_t)row * DIM + (k0 + 32) + sc4 * 4);
        vb[r2] = *(const float4v*)(srcB + (size_t)row * DIM + (k0 + 32) + sc4 * 4);
      }
    }
    __syncthreads();
    // phase 3: frags + MFMA (B hoisted, A per-m to limit VGPR peak)
    bf16x8 fbh[4], fbl[4];
#pragma unroll
    for (int n = 0; n < 4; ++n) {
      const int row = wsd * 64 + n * 16 + r16;
      fbh[n] = *(const bf16x8*)(bHi + row * LP + g * 8);
      fbl[n] = *(const bf16x8*)(bLo + row * LP + g * 8);
    }
#pragma unroll
    for (int m = 0; m < 4; ++m) {
      const int row = wt * 64 + m * 16 + r16;
      bf16x8 fah = *(const bf16x8*)(aHi + row * LP + g * 8);
      bf16x8 fal = *(const bf16x8*)(aLo + row * LP + g * 8);
#pragma unroll
      for (int n = 0; n < 4; ++n) {
        acc[m][n] = __builtin_amdgcn_mfma_f32_16x16x32_bf16(fah, fbh[n], acc[m][n], 0, 0, 0);
        acc[m][n] = __builtin_amdgcn_mfma_f32_16x16x32_bf16(fal, fbh[n], acc[m][n], 0, 0, 0);
        acc[m][n] = __builtin_amdgcn_mfma_f32_16x16x32_bf16(fah, fbl[n], acc[m][n], 0, 0, 0);
      }
    }
    __syncthreads();
  }
  float* outB = align_out + ((size_t)(b * TLEN + t0)) * SLEN + s0;
#pragma unroll
  for (int m = 0; m < 4; ++m) {
    const int tr = wt * 64 + m * 16 + g * 4;
#pragma unroll
    for (int n = 0; n < 4; ++n) {
      const int sc = wsd * 64 + n * 16 + r16;
#pragma unroll
      for (int rr = 0; rr < 4; ++rr)
        outB[(size_t)(tr + rr) * SLEN + sc] = acc[m][n][rr];
    }
  }
}

// ---------------------------------------------------------------- K2: masked softmax (in-place)
__global__ __launch_bounds__(256) void k_softmax(
    const int* __restrict__ lens, float* __restrict__ align_io) {
  const int row  = blockIdx.x * 4 + (threadIdx.x >> 6);  // b*1024 + t
  const int lane = threadIdx.x & 63;
  const int b    = row >> 10;
  const int len  = get_len(lens, b);
  float* p = align_io + (size_t)row * SLEN;
  float v[4][4];
  float mx = -3.0e38f;
#pragma unroll
  for (int q = 0; q < 4; ++q) {
    if (256 * q >= len) {
#pragma unroll
      for (int j = 0; j < 4; ++j) v[q][j] = 0.f;
      continue;
    }
    const int sb = (lane + 64 * q) * 4;
    float4v x = *(const float4v*)(p + sb);
#pragma unroll
    for (int j = 0; j < 4; ++j) {
      v[q][j] = (sb + j < len) ? x[j] : 0.f;
      if (sb + j < len) mx = fmaxf(mx, x[j]);
    }
  }
#pragma unroll
  for (int off = 1; off < 64; off <<= 1) mx = fmaxf(mx, __shfl_xor(mx, off));
  float sum = 0.f;
#pragma unroll
  for (int q = 0; q < 4; ++q) {
    const int sb = (lane + 64 * q) * 4;
#pragma unroll
    for (int j = 0; j < 4; ++j) {
      float e = (sb + j < len) ? __expf(v[q][j] - mx) : 0.f;
      v[q][j] = e; sum += e;
    }
  }
#pragma unroll
  for (int off = 1; off < 64; off <<= 1) sum += __shfl_xor(sum, off);
  const float inv = 1.f / sum;
#pragma unroll
  for (int q = 0; q < 4; ++q) {
    float4v x;
#pragma unroll
    for (int j = 0; j < 4; ++j) x[j] = v[q][j] * inv;
    *(float4v*)(p + (lane + 64 * q) * 4) = x;
  }
}

// ---------------------------------------------------------------- K3: c = align @ src (bf16, K clamped, prefetch, sorted-z)
__global__ __launch_bounds__(256) void k_pv(
    const float* __restrict__ align_in, const unsigned short* __restrict__ srcT,
    const int* __restrict__ lens, const int* __restrict__ meta,
    unsigned short* __restrict__ cws) {
  const int b  = meta[blockIdx.z];       // sorted: longest batches dispatch first
  const int t0 = blockIdx.x * TILE;
  const int d0 = blockIdx.y * TILE;
  const int len = get_len(lens, b);
  const int ksteps = (len + 31) >> 5;

  __shared__ short A[TILE * LP], B[TILE * LP];
  const int tid  = threadIdx.x;
  const int lane = tid & 63;
  const int wid  = tid >> 6;
  const int wt   = wid >> 1, wsd = wid & 1;
  const int g    = lane >> 4, r16 = lane & 15;

  f32x4 acc[4][4];
#pragma unroll
  for (int m = 0; m < 4; ++m)
#pragma unroll
    for (int n = 0; n < 4; ++n) acc[m][n] = (f32x4){0.f, 0.f, 0.f, 0.f};

  const int arow = tid >> 3, ac4 = tid & 7;
  const int brow = tid >> 2, bc8 = tid & 3;

  float4v xa[4];
  bf16x8  xb[2];
#pragma unroll
  for (int r = 0; r < 4; ++r)
    xa[r] = *(const float4v*)(align_in + ((size_t)(b * TLEN + t0 + arow + 32 * r)) * SLEN + ac4 * 4);
#pragma unroll
  for (int r = 0; r < 2; ++r)
    xb[r] = *(const bf16x8*)(srcT + ((size_t)(b * DIM + d0 + brow + 64 * r)) * SLEN + bc8 * 8);

  for (int ks = 0; ks < ksteps; ++ks) {
#pragma unroll
    for (int r = 0; r < 4; ++r) {   // A: align rows t (trunc-bf16 ok: align in [0,1])
      u32x2 h;
      h[0] = packhi(xa[r][0], xa[r][1]); h[1] = packhi(xa[r][2], xa[r][3]);
      *(u32x2*)(A + (arow + 32 * r) * LP + ac4 * 4) = h;
    }
#pragma unroll
    for (int r = 0; r < 2; ++r)     // B: srcT rows d
      *(bf16x8*)(B + (brow + 64 * r) * LP + bc8 * 8) = xb[r];
    if (ks + 1 < ksteps) {
      const int k0 = (ks + 1) * 32;
#pragma unroll
      for (int r = 0; r < 4; ++r)
        xa[r] = *(const float4v*)(align_in + ((size_t)(b * TLEN + t0 + arow + 32 * r)) * SLEN + k0 + ac4 * 4);
#pragma unroll
      for (int r = 0; r < 2; ++r)
        xb[r] = *(const bf16x8*)(srcT + ((size_t)(b * DIM + d0 + brow + 64 * r)) * SLEN + k0 + bc8 * 8);
    }
    __syncthreads();
    bf16x8 fb[4];
#pragma unroll
    for (int n = 0; n < 4; ++n) fb[n] = *(const bf16x8*)(B + (wsd * 64 + n * 16 + r16) * LP + g * 8);
#pragma unroll
    for (int m = 0; m < 4; ++m) {
      bf16x8 fa = *(const bf16x8*)(A + (wt * 64 + m * 16 + r16) * LP + g * 8);
#pragma unroll
      for (int n = 0; n < 4; ++n)
        acc[m][n] = __builtin_amdgcn_mfma_f32_16x16x32_bf16(fa, fb[n], acc[m][n], 0, 0, 0);
    }
    __syncthreads();
  }
#pragma unroll
  for (int m = 0; m < 4; ++m) {
    const int tr = wt * 64 + m * 16 + g * 4;
#pragma unroll
    for (int n = 0; n < 4; ++n) {
      const int dc = wsd * 64 + n * 16 + r16;
#pragma unroll
      for (int r = 0; r < 4; ++r)
        cws[((size_t)(b * TLEN + t0 + tr + r)) * DIM + d0 + dc] = f2bf(acc[m][n][r]);
    }
  }
}

// ---------------------------------------------------------------- K4: attn_h = [c,tgt] @ w_out^T (bf16)
__global__ __launch_bounds__(256) void k_proj(
    const unsigned short* __restrict__ cws, const float* __restrict__ tgt,
    const unsigned short* __restrict__ wbf, float* __restrict__ attn_out) {
  const int b  = blockIdx.z;
  const int t0 = blockIdx.x * TILE;
  const int d0 = blockIdx.y * TILE;

  __shared__ short A[TILE * LP], B[TILE * LP];
  const int tid  = threadIdx.x;
  const int lane = tid & 63;
  const int wid  = tid >> 6;
  const int wt   = wid >> 1, wsd = wid & 1;
  const int g    = lane >> 4, r16 = lane & 15;

  f32x4 acc[4][4];
#pragma unroll
  for (int m = 0; m < 4; ++m)
#pragma unroll
    for (int n = 0; n < 4; ++n) acc[m][n] = (f32x4){0.f, 0.f, 0.f, 0.f};

  for (int k0 = 0; k0 < 2 * DIM; k0 += 32) {
    if (k0 < DIM) {   // A from c (already bf16)
#pragma unroll
      for (int r = 0; r < 2; ++r) {
        const int row = (tid >> 2) + 64 * r, c8 = tid & 3;
        bf16x8 x = *(const bf16x8*)(cws + ((size_t)(b * TLEN + t0 + row)) * DIM + k0 + c8 * 8);
        *(bf16x8*)(A + row * LP + c8 * 8) = x;
      }
    } else {          // A from tgt (f32 -> bf16 RNE, margin for the fp32 output)
#pragma unroll
      for (int r = 0; r < 4; ++r) {
        const int row = (tid >> 3) + 32 * r, c4 = tid & 7;
        float4v x = *(const float4v*)(tgt + ((size_t)(b * TLEN + t0 + row)) * DIM + (k0 - DIM) + c4 * 4);
        bf16x4 h;
#pragma unroll
        for (int j = 0; j < 4; ++j) h[j] = (short)f2bf(x[j]);
        *(bf16x4*)(A + row * LP + c4 * 4) = h;
      }
    }
#pragma unroll
    for (int r = 0; r < 2; ++r) {   // B: wbf rows d, cols e (bf16 copy)
      const int row = (tid >> 2) + 64 * r, c8 = tid & 3;
      bf16x8 x = *(const bf16x8*)(wbf + ((size_t)(d0 + row)) * (2 * DIM) + k0 + c8 * 8);
      *(bf16x8*)(B + row * LP + c8 * 8) = x;
    }
    __syncthreads();
    bf16x8 fb[4];
#pragma unroll
    for (int n = 0; n < 4; ++n) fb[n] = *(const bf16x8*)(B + (wsd * 64 + n * 16 + r16) * LP + g * 8);
#pragma unroll
    for (int m = 0; m < 4; ++m) {
      bf16x8 fa = *(const bf16x8*)(A + (wt * 64 + m * 16 + r16) * LP + g * 8);
#pragma unroll
      for (int n = 0; n < 4; ++n)
        acc[m][n] = __builtin_amdgcn_mfma_f32_16x16x32_bf16(fa, fb[n], acc[m][n], 0, 0, 0);
    }
    __syncthreads();
  }
#pragma unroll
  for (int m = 0; m < 4; ++m) {
    const int tr = wt * 64 + m * 16 + g * 4;
#pragma unroll
    for (int n = 0; n < 4; ++n) {
      const int dc = wsd * 64 + n * 16 + r16;
#pragma unroll
      for (int r = 0; r < 4; ++r)
        attn_out[((size_t)(b * TLEN + t0 + tr + r)) * DIM + d0 + dc] = acc[m][n][r];
    }
  }
}

extern "C" void kernel_launch(void* const* d_in, const int* in_sizes, int n_in,
                              void* d_out, int out_size, void* d_ws, size_t ws_size,
                              hipStream_t stream) {
  const float* src   = (const float*)d_in[0];
  const float* tgt   = (const float*)d_in[1];
  const int*   lens  = (const int*)d_in[2];
  const float* w_out = (const float*)d_in[3];

  float* attn_out  = (float*)d_out;                          // 32*1024*512 f32
  float* align_out = attn_out + (size_t)BZ * TLEN * DIM;     // 32*1024*1024 f32

  const size_t NE = (size_t)BZ * SLEN * DIM;
  const size_t NW = (size_t)DIM * 2 * DIM;
  unsigned short* srcT = (unsigned short*)d_ws;
  unsigned short* cws  = srcT + NE;
  unsigned short* wbf  = cws + NE;
  int*            meta = (int*)(wbf + NW);

  k_count<<<dim3(1), 64, 0, stream>>>(lens, meta);
  k_transpose<<<dim3(16, 8, BZ), 256, 0, stream>>>(src, srcT);
  k_prep_w<<<dim3((unsigned)(NW / 8 / 256)), 256, 0, stream>>>(w_out, wbf);
  k_score<<<dim3(2048), 256, 0, stream>>>(tgt, src, meta, align_out);
  k_softmax<<<dim3(BZ * TLEN / 4), 256, 0, stream>>>(lens, align_out);
  k_pv<<<dim3(8, 4, BZ), 256, 0, stream>>>(align_out, srcT, lens, meta, cws);
  k_proj<<<dim3(8, 4, BZ), 256, 0, stream>>>(cws, tgt, wbf, attn_out);
}

// Round 10
// 265.258 us; speedup vs baseline: 1.9157x; 1.0168x over previous
//
#include <hip/hip_runtime.h>
#include <hip/hip_bf16.h>

typedef __attribute__((ext_vector_type(4))) float  f32x4;
typedef __attribute__((ext_vector_type(4))) float  float4v;
typedef __attribute__((ext_vector_type(8))) short  bf16x8;
typedef __attribute__((ext_vector_type(4))) short  bf16x4;
typedef __attribute__((ext_vector_type(2))) unsigned int u32x2;

#define BZ   32
#define SLEN 1024
#define TLEN 1024
#define DIM  512
#define TILE 128
#define TM   64   // k_score t-tile (smaller -> 30KB LDS -> 2 blocks/CU)
#define LP   40   // LDS row pitch (shorts): 80B rows

// v_perm selector: out = [hi16(src0_arg) : hi16(src1_arg)]
#define PSEL 0x07060302u

__device__ __forceinline__ unsigned int fbits(float x) { return __builtin_bit_cast(unsigned int, x); }
__device__ __forceinline__ float fval(unsigned int u) { return __builtin_bit_cast(float, u); }

__device__ __forceinline__ unsigned short f2bf(float x) {   // RNE (off hot path)
  unsigned int u = fbits(x);
  unsigned int r = u + 0x7FFFu + ((u >> 16) & 1u);
  return (unsigned short)(r >> 16);
}
__device__ __forceinline__ float bf2f(unsigned short h) { return fval(((unsigned int)h) << 16); }

// pack trunc-bf16 of (x0,x1) -> u32 [bf(x1)<<16 | bf(x0)]
__device__ __forceinline__ unsigned int packhi(float x0, float x1) {
  return __builtin_amdgcn_perm(fbits(x1), fbits(x0), PSEL);
}

// src_lengths may land as int64 or int32; values are in [1,1024] so in the
// int64 layout every odd 32-bit word is 0, while int32 layout has p[1]>=1.
__device__ __forceinline__ int get_len(const int* __restrict__ p, int b) {
  bool is64 = (p[1] == 0) && (p[3] == 0) && (p[5] == 0);
  return is64 ? p[2 * b] : p[b];
}

// ---------------------------------------------------------------- K0: src -> srcT (bf16)
#define TLP 68
__global__ __launch_bounds__(256) void k_transpose(
    const float* __restrict__ src, unsigned short* __restrict__ srcT) {
  const int b  = blockIdx.z;
  const int s0 = blockIdx.x * 64;
  const int d0 = blockIdx.y * 64;
  __shared__ unsigned short tl[64 * TLP];
  const int tid = threadIdx.x;
#pragma unroll
  for (int r = 0; r < 4; ++r) {
    const int idx = tid + 256 * r;
    const int row = idx >> 4, c4 = idx & 15;   // row: s, c4: d/4
    float4v x = *(const float4v*)(src + ((size_t)(b * SLEN + s0 + row)) * DIM + d0 + c4 * 4);
    unsigned short* pp = tl + row * TLP + c4 * 4;
    pp[0] = f2bf(x[0]); pp[1] = f2bf(x[1]); pp[2] = f2bf(x[2]); pp[3] = f2bf(x[3]);
  }
  __syncthreads();
#pragma unroll
  for (int r = 0; r < 2; ++r) {
    const int idx  = tid + 256 * r;
    const int drow = idx >> 3, c8 = idx & 7;   // drow: d, c8: s/8
    union { unsigned short u[8]; bf16x8 v; } pk;
#pragma unroll
    for (int j = 0; j < 8; ++j) pk.u[j] = tl[(c8 * 8 + j) * TLP + drow];
    *(bf16x8*)(srcT + ((size_t)(b * DIM + d0 + drow)) * SLEN + s0 + c8 * 8) = pk.v;
  }
}

// ---------------------------------------------------------------- prep: w_out -> bf16 (RNE)
__global__ __launch_bounds__(256) void k_prep_w(
    const float* __restrict__ w, unsigned short* __restrict__ wbf) {
  const size_t i = ((size_t)blockIdx.x * 256 + threadIdx.x) * 8;
  float4v x0 = *(const float4v*)(w + i);
  float4v x1 = *(const float4v*)(w + i + 4);
  union { unsigned short u[8]; bf16x8 v; } hi;
#pragma unroll
  for (int j = 0; j < 4; ++j) { hi.u[j] = f2bf(x0[j]); hi.u[4 + j] = f2bf(x1[j]); }
  *(bf16x8*)(wbf + i) = hi.v;
}

// ---------------------------------------------------------------- K1: score = tgt @ src^T (3xbf16, trunc-split)
// 64t x 128s tile, 30KB LDS -> 2 blocks/CU co-resident. 4 waves, each a
// 64x32 output slice (A-frags shared). Reg-prefetch pipeline as R5.
__global__ __launch_bounds__(256) void k_score(
    const float* __restrict__ tgt, const float* __restrict__ src,
    const int* __restrict__ lens, float* __restrict__ align_out) {
  const int b  = blockIdx.z;
  const int t0 = blockIdx.x * TM;
  const int s0 = blockIdx.y * TILE;
  const int len = get_len(lens, b);
  if (s0 >= len) return;   // fully-masked tile: softmax writes the zeros

  __shared__ short aHi[TM * LP], aLo[TM * LP], bHi[TILE * LP], bLo[TILE * LP];

  const int tid  = threadIdx.x;
  const int lane = tid & 63;
  const int wsd  = tid >> 6;                   // wave -> 32-col B slice
  const int g    = lane >> 4, r16 = lane & 15;
  const int srow = tid >> 3, sc4 = tid & 7;

  f32x4 acc[4][2];
#pragma unroll
  for (int m = 0; m < 4; ++m)
#pragma unroll
    for (int n = 0; n < 2; ++n) acc[m][n] = (f32x4){0.f, 0.f, 0.f, 0.f};

  const float* tgtB = tgt + ((size_t)(b * TLEN + t0)) * DIM;
  const float* srcB = src + ((size_t)(b * SLEN + s0)) * DIM;

  float4v va[2], vb[4];
#pragma unroll
  for (int r2 = 0; r2 < 2; ++r2)
    va[r2] = *(const float4v*)(tgtB + (size_t)(srow + 32 * r2) * DIM + sc4 * 4);
#pragma unroll
  for (int r2 = 0; r2 < 4; ++r2)
    vb[r2] = *(const float4v*)(srcB + (size_t)(srow + 32 * r2) * DIM + sc4 * 4);

  for (int k0 = 0; k0 < DIM; k0 += 32) {
    // phase 1: convert current regs -> LDS
#pragma unroll
    for (int r2 = 0; r2 < 2; ++r2) {
      const int row = srow + 32 * r2;
      u32x2 h, l;
      h[0] = packhi(va[r2][0], va[r2][1]); h[1] = packhi(va[r2][2], va[r2][3]);
      float q0 = va[r2][0] - fval(fbits(va[r2][0]) & 0xFFFF0000u);
      float q1 = va[r2][1] - fval(fbits(va[r2][1]) & 0xFFFF0000u);
      float q2 = va[r2][2] - fval(fbits(va[r2][2]) & 0xFFFF0000u);
      float q3 = va[r2][3] - fval(fbits(va[r2][3]) & 0xFFFF0000u);
      l[0] = packhi(q0, q1); l[1] = packhi(q2, q3);
      const int o = row * LP + sc4 * 4;
      *(u32x2*)(aHi + o) = h; *(u32x2*)(aLo + o) = l;
    }
#pragma unroll
    for (int r2 = 0; r2 < 4; ++r2) {
      const int row = srow + 32 * r2;
      u32x2 h, l;
      h[0] = packhi(vb[r2][0], vb[r2][1]); h[1] = packhi(vb[r2][2], vb[r2][3]);
      float q0 = vb[r2][0] - fval(fbits(vb[r2][0]) & 0xFFFF0000u);
      float q1 = vb[r2][1] - fval(fbits(vb[r2][1]) & 0xFFFF0000u);
      float q2 = vb[r2][2] - fval(fbits(vb[r2][2]) & 0xFFFF0000u);
      float q3 = vb[r2][3] - fval(fbits(vb[r2][3]) & 0xFFFF0000u);
      l[0] = packhi(q0, q1); l[1] = packhi(q2, q3);
      const int o = row * LP + sc4 * 4;
      *(u32x2*)(bHi + o) = h; *(u32x2*)(bLo + o) = l;
    }
    // phase 2: issue next K-step loads (consumed after MFMA+barrier)
    if (k0 + 32 < DIM) {
#pragma unroll
      for (int r2 = 0; r2 < 2; ++r2)
        va[r2] = *(const float4v*)(tgtB + (size_t)(srow + 32 * r2) * DIM + (k0 + 32) + sc4 * 4);
#pragma unroll
      for (int r2 = 0; r2 < 4; ++r2)
        vb[r2] = *(const float4v*)(srcB + (size_t)(srow + 32 * r2) * DIM + (k0 + 32) + sc4 * 4);
    }
    __syncthreads();
    // phase 3: frags + MFMA
    bf16x8 fbh[2], fbl[2];
#pragma unroll
    for (int n = 0; n < 2; ++n) {
      const int row = wsd * 32 + n * 16 + r16;
      fbh[n] = *(const bf16x8*)(bHi + row * LP + g * 8);
      fbl[n] = *(const bf16x8*)(bLo + row * LP + g * 8);
    }
#pragma unroll
    for (int m = 0; m < 4; ++m) {
      const int row = m * 16 + r16;
      bf16x8 fah = *(const bf16x8*)(aHi + row * LP + g * 8);
      bf16x8 fal = *(const bf16x8*)(aLo + row * LP + g * 8);
#pragma unroll
      for (int n = 0; n < 2; ++n) {
        acc[m][n] = __builtin_amdgcn_mfma_f32_16x16x32_bf16(fah, fbh[n], acc[m][n], 0, 0, 0);
        acc[m][n] = __builtin_amdgcn_mfma_f32_16x16x32_bf16(fal, fbh[n], acc[m][n], 0, 0, 0);
        acc[m][n] = __builtin_amdgcn_mfma_f32_16x16x32_bf16(fah, fbl[n], acc[m][n], 0, 0, 0);
      }
    }
    __syncthreads();
  }
  float* outB = align_out + ((size_t)(b * TLEN + t0)) * SLEN + s0;
#pragma unroll
  for (int m = 0; m < 4; ++m) {
    const int tr = m * 16 + g * 4;
#pragma unroll
    for (int n = 0; n < 2; ++n) {
      const int sc = wsd * 32 + n * 16 + r16;
#pragma unroll
      for (int rr = 0; rr < 4; ++rr)
        outB[(size_t)(tr + rr) * SLEN + sc] = acc[m][n][rr];
    }
  }
}

// ---------------------------------------------------------------- K2: masked softmax (in-place)
__global__ __launch_bounds__(256) void k_softmax(
    const int* __restrict__ lens, float* __restrict__ align_io) {
  const int row  = blockIdx.x * 4 + (threadIdx.x >> 6);  // b*1024 + t
  const int lane = threadIdx.x & 63;
  const int b    = row >> 10;
  const int len  = get_len(lens, b);
  float* p = align_io + (size_t)row * SLEN;
  float v[4][4];
  float mx = -3.0e38f;
#pragma unroll
  for (int q = 0; q < 4; ++q) {
    if (256 * q >= len) {
#pragma unroll
      for (int j = 0; j < 4; ++j) v[q][j] = 0.f;
      continue;
    }
    const int sb = (lane + 64 * q) * 4;
    float4v x = *(const float4v*)(p + sb);
#pragma unroll
    for (int j = 0; j < 4; ++j) {
      v[q][j] = (sb + j < len) ? x[j] : 0.f;
      if (sb + j < len) mx = fmaxf(mx, x[j]);
    }
  }
#pragma unroll
  for (int off = 1; off < 64; off <<= 1) mx = fmaxf(mx, __shfl_xor(mx, off));
  float sum = 0.f;
#pragma unroll
  for (int q = 0; q < 4; ++q) {
    const int sb = (lane + 64 * q) * 4;
#pragma unroll
    for (int j = 0; j < 4; ++j) {
      float e = (sb + j < len) ? __expf(v[q][j] - mx) : 0.f;
      v[q][j] = e; sum += e;
    }
  }
#pragma unroll
  for (int off = 1; off < 64; off <<= 1) sum += __shfl_xor(sum, off);
  const float inv = 1.f / sum;
#pragma unroll
  for (int q = 0; q < 4; ++q) {
    float4v x;
#pragma unroll
    for (int j = 0; j < 4; ++j) x[j] = v[q][j] * inv;
    *(float4v*)(p + (lane + 64 * q) * 4) = x;
  }
}

// ---------------------------------------------------------------- K3: c = align @ src (bf16, K clamped, prefetch)
__global__ __launch_bounds__(256) void k_pv(
    const float* __restrict__ align_in, const unsigned short* __restrict__ srcT,
    const int* __restrict__ lens, unsigned short* __restrict__ cws) {
  const int b  = blockIdx.z;
  const int t0 = blockIdx.x * TILE;
  const int d0 = blockIdx.y * TILE;
  const int len = get_len(lens, b);
  const int ksteps = (len + 31) >> 5;

  __shared__ short A[TILE * LP], B[TILE * LP];
  const int tid  = threadIdx.x;
  const int lane = tid & 63;
  const int wid  = tid >> 6;
  const int wt   = wid >> 1, wsd = wid & 1;
  const int g    = lane >> 4, r16 = lane & 15;

  f32x4 acc[4][4];
#pragma unroll
  for (int m = 0; m < 4; ++m)
#pragma unroll
    for (int n = 0; n < 4; ++n) acc[m][n] = (f32x4){0.f, 0.f, 0.f, 0.f};

  const int arow = tid >> 3, ac4 = tid & 7;
  const int brow = tid >> 2, bc8 = tid & 3;

  float4v xa[4];
  bf16x8  xb[2];
#pragma unroll
  for (int r = 0; r < 4; ++r)
    xa[r] = *(const float4v*)(align_in + ((size_t)(b * TLEN + t0 + arow + 32 * r)) * SLEN + ac4 * 4);
#pragma unroll
  for (int r = 0; r < 2; ++r)
    xb[r] = *(const bf16x8*)(srcT + ((size_t)(b * DIM + d0 + brow + 64 * r)) * SLEN + bc8 * 8);

  for (int ks = 0; ks < ksteps; ++ks) {
#pragma unroll
    for (int r = 0; r < 4; ++r) {   // A: align rows t (trunc-bf16 ok: align in [0,1])
      u32x2 h;
      h[0] = packhi(xa[r][0], xa[r][1]); h[1] = packhi(xa[r][2], xa[r][3]);
      *(u32x2*)(A + (arow + 32 * r) * LP + ac4 * 4) = h;
    }
#pragma unroll
    for (int r = 0; r < 2; ++r)     // B: srcT rows d
      *(bf16x8*)(B + (brow + 64 * r) * LP + bc8 * 8) = xb[r];
    if (ks + 1 < ksteps) {
      const int k0 = (ks + 1) * 32;
#pragma unroll
      for (int r = 0; r < 4; ++r)
        xa[r] = *(const float4v*)(align_in + ((size_t)(b * TLEN + t0 + arow + 32 * r)) * SLEN + k0 + ac4 * 4);
#pragma unroll
      for (int r = 0; r < 2; ++r)
        xb[r] = *(const bf16x8*)(srcT + ((size_t)(b * DIM + d0 + brow + 64 * r)) * SLEN + k0 + bc8 * 8);
    }
    __syncthreads();
    bf16x8 fb[4];
#pragma unroll
    for (int n = 0; n < 4; ++n) fb[n] = *(const bf16x8*)(B + (wsd * 64 + n * 16 + r16) * LP + g * 8);
#pragma unroll
    for (int m = 0; m < 4; ++m) {
      bf16x8 fa = *(const bf16x8*)(A + (wt * 64 + m * 16 + r16) * LP + g * 8);
#pragma unroll
      for (int n = 0; n < 4; ++n)
        acc[m][n] = __builtin_amdgcn_mfma_f32_16x16x32_bf16(fa, fb[n], acc[m][n], 0, 0, 0);
    }
    __syncthreads();
  }
#pragma unroll
  for (int m = 0; m < 4; ++m) {
    const int tr = wt * 64 + m * 16 + g * 4;
#pragma unroll
    for (int n = 0; n < 4; ++n) {
      const int dc = wsd * 64 + n * 16 + r16;
#pragma unroll
      for (int r = 0; r < 4; ++r)
        cws[((size_t)(b * TLEN + t0 + tr + r)) * DIM + d0 + dc] = f2bf(acc[m][n][r]);
    }
  }
}

// ---------------------------------------------------------------- K4: attn_h = [c,tgt] @ w_out^T (bf16)
__global__ __launch_bounds__(256) void k_proj(
    const unsigned short* __restrict__ cws, const float* __restrict__ tgt,
    const unsigned short* __restrict__ wbf, float* __restrict__ attn_out) {
  const int b  = blockIdx.z;
  const int t0 = blockIdx.x * TILE;
  const int d0 = blockIdx.y * TILE;

  __shared__ short A[TILE * LP], B[TILE * LP];
  const int tid  = threadIdx.x;
  const int lane = tid & 63;
  const int wid  = tid >> 6;
  const int wt   = wid >> 1, wsd = wid & 1;
  const int g    = lane >> 4, r16 = lane & 15;

  f32x4 acc[4][4];
#pragma unroll
  for (int m = 0; m < 4; ++m)
#pragma unroll
    for (int n = 0; n < 4; ++n) acc[m][n] = (f32x4){0.f, 0.f, 0.f, 0.f};

  for (int k0 = 0; k0 < 2 * DIM; k0 += 32) {
    if (k0 < DIM) {   // A from c (already bf16)
#pragma unroll
      for (int r = 0; r < 2; ++r) {
        const int row = (tid >> 2) + 64 * r, c8 = tid & 3;
        bf16x8 x = *(const bf16x8*)(cws + ((size_t)(b * TLEN + t0 + row)) * DIM + k0 + c8 * 8);
        *(bf16x8*)(A + row * LP + c8 * 8) = x;
      }
    } else {          // A from tgt (f32 -> bf16 RNE, margin for the fp32 output)
#pragma unroll
      for (int r = 0; r < 4; ++r) {
        const int row = (tid >> 3) + 32 * r, c4 = tid & 7;
        float4v x = *(const float4v*)(tgt + ((size_t)(b * TLEN + t0 + row)) * DIM + (k0 - DIM) + c4 * 4);
        bf16x4 h;
#pragma unroll
        for (int j = 0; j < 4; ++j) h[j] = (short)f2bf(x[j]);
        *(bf16x4*)(A + row * LP + c4 * 4) = h;
      }
    }
#pragma unroll
    for (int r = 0; r < 2; ++r) {   // B: wbf rows d, cols e (bf16 copy)
      const int row = (tid >> 2) + 64 * r, c8 = tid & 3;
      bf16x8 x = *(const bf16x8*)(wbf + ((size_t)(d0 + row)) * (2 * DIM) + k0 + c8 * 8);
      *(bf16x8*)(B + row * LP + c8 * 8) = x;
    }
    __syncthreads();
    bf16x8 fb[4];
#pragma unroll
    for (int n = 0; n < 4; ++n) fb[n] = *(const bf16x8*)(B + (wsd * 64 + n * 16 + r16) * LP + g * 8);
#pragma unroll
    for (int m = 0; m < 4; ++m) {
      bf16x8 fa = *(const bf16x8*)(A + (wt * 64 + m * 16 + r16) * LP + g * 8);
#pragma unroll
      for (int n = 0; n < 4; ++n)
        acc[m][n] = __builtin_amdgcn_mfma_f32_16x16x32_bf16(fa, fb[n], acc[m][n], 0, 0, 0);
    }
    __syncthreads();
  }
#pragma unroll
  for (int m = 0; m < 4; ++m) {
    const int tr = wt * 64 + m * 16 + g * 4;
#pragma unroll
    for (int n = 0; n < 4; ++n) {
      const int dc = wsd * 64 + n * 16 + r16;
#pragma unroll
      for (int r = 0; r < 4; ++r)
        attn_out[((size_t)(b * TLEN + t0 + tr + r)) * DIM + d0 + dc] = acc[m][n][r];
    }
  }
}

extern "C" void kernel_launch(void* const* d_in, const int* in_sizes, int n_in,
                              void* d_out, int out_size, void* d_ws, size_t ws_size,
                              hipStream_t stream) {
  const float* src   = (const float*)d_in[0];
  const float* tgt   = (const float*)d_in[1];
  const int*   lens  = (const int*)d_in[2];
  const float* w_out = (const float*)d_in[3];

  float* attn_out  = (float*)d_out;                          // 32*1024*512 f32
  float* align_out = attn_out + (size_t)BZ * TLEN * DIM;     // 32*1024*1024 f32

  const size_t NE = (size_t)BZ * SLEN * DIM;
  const size_t NW = (size_t)DIM * 2 * DIM;
  unsigned short* srcT = (unsigned short*)d_ws;
  unsigned short* cws  = srcT + NE;
  unsigned short* wbf  = cws + NE;

  k_transpose<<<dim3(16, 8, BZ), 256, 0, stream>>>(src, srcT);
  k_prep_w<<<dim3((unsigned)(NW / 8 / 256)), 256, 0, stream>>>(w_out, wbf);
  k_score<<<dim3(16, 8, BZ), 256, 0, stream>>>(tgt, src, lens, align_out);
  k_softmax<<<dim3(BZ * TLEN / 4), 256, 0, stream>>>(lens, align_out);
  k_pv<<<dim3(8, 4, BZ), 256, 0, stream>>>(align_out, srcT, lens, cws);
  k_proj<<<dim3(8, 4, BZ), 256, 0, stream>>>(cws, tgt, wbf, attn_out);
}

// Round 11
// 262.960 us; speedup vs baseline: 1.9324x; 1.0087x over previous
//
#include <hip/hip_runtime.h>
#include <hip/hip_bf16.h>

typedef __attribute__((ext_vector_type(4))) float  f32x4;
typedef __attribute__((ext_vector_type(4))) float  float4v;
typedef __attribute__((ext_vector_type(8))) short  bf16x8;
typedef __attribute__((ext_vector_type(4))) short  bf16x4;
typedef __attribute__((ext_vector_type(2))) unsigned int u32x2;

#define BZ   32
#define SLEN 1024
#define TLEN 1024
#define DIM  512
#define TILE 128
#define LP   40   // LDS row pitch (shorts): 80B rows (R5 best config)

// v_perm selector: out = [hi16(src0_arg) : hi16(src1_arg)]
#define PSEL 0x07060302u

__device__ __forceinline__ unsigned int fbits(float x) { return __builtin_bit_cast(unsigned int, x); }
__device__ __forceinline__ float fval(unsigned int u) { return __builtin_bit_cast(float, u); }

__device__ __forceinline__ unsigned short f2bf(float x) {   // RNE (off hot path)
  unsigned int u = fbits(x);
  unsigned int r = u + 0x7FFFu + ((u >> 16) & 1u);
  return (unsigned short)(r >> 16);
}
__device__ __forceinline__ float bf2f(unsigned short h) { return fval(((unsigned int)h) << 16); }

// pack trunc-bf16 of (x0,x1) -> u32 [bf(x1)<<16 | bf(x0)]
__device__ __forceinline__ unsigned int packhi(float x0, float x1) {
  return __builtin_amdgcn_perm(fbits(x1), fbits(x0), PSEL);
}

// src_lengths may land as int64 or int32; values are in [1,1024] so in the
// int64 layout every odd 32-bit word is 0, while int32 layout has p[1]>=1.
__device__ __forceinline__ int get_len(const int* __restrict__ p, int b) {
  bool is64 = (p[1] == 0) && (p[3] == 0) && (p[5] == 0);
  return is64 ? p[2 * b] : p[b];
}

// ---------------------------------------------------------------- K0: src -> srcT (bf16)
#define TLP 68
__global__ __launch_bounds__(256) void k_transpose(
    const float* __restrict__ src, unsigned short* __restrict__ srcT) {
  const int b  = blockIdx.z;
  const int s0 = blockIdx.x * 64;
  const int d0 = blockIdx.y * 64;
  __shared__ unsigned short tl[64 * TLP];
  const int tid = threadIdx.x;
#pragma unroll
  for (int r = 0; r < 4; ++r) {
    const int idx = tid + 256 * r;
    const int row = idx >> 4, c4 = idx & 15;   // row: s, c4: d/4
    float4v x = *(const float4v*)(src + ((size_t)(b * SLEN + s0 + row)) * DIM + d0 + c4 * 4);
    unsigned short* pp = tl + row * TLP + c4 * 4;
    pp[0] = f2bf(x[0]); pp[1] = f2bf(x[1]); pp[2] = f2bf(x[2]); pp[3] = f2bf(x[3]);
  }
  __syncthreads();
#pragma unroll
  for (int r = 0; r < 2; ++r) {
    const int idx  = tid + 256 * r;
    const int drow = idx >> 3, c8 = idx & 7;   // drow: d, c8: s/8
    union { unsigned short u[8]; bf16x8 v; } pk;
#pragma unroll
    for (int j = 0; j < 8; ++j) pk.u[j] = tl[(c8 * 8 + j) * TLP + drow];
    *(bf16x8*)(srcT + ((size_t)(b * DIM + d0 + drow)) * SLEN + s0 + c8 * 8) = pk.v;
  }
}

// ---------------------------------------------------------------- prep: w_out -> bf16 (RNE)
__global__ __launch_bounds__(256) void k_prep_w(
    const float* __restrict__ w, unsigned short* __restrict__ wbf) {
  const size_t i = ((size_t)blockIdx.x * 256 + threadIdx.x) * 8;
  float4v x0 = *(const float4v*)(w + i);
  float4v x1 = *(const float4v*)(w + i + 4);
  union { unsigned short u[8]; bf16x8 v; } hi;
#pragma unroll
  for (int j = 0; j < 4; ++j) { hi.u[j] = f2bf(x0[j]); hi.u[4 + j] = f2bf(x1[j]); }
  *(bf16x8*)(wbf + i) = hi.v;
}

// ---------------------------------------------------------------- K1: score = tgt @ src^T (3xbf16, trunc-split)
// R5 body + batch->XCD pinned dispatch: all tiles of batch b land on XCD b%8
// (round-robin dispatch), so src+tgt panels (4MB/batch) stay in that L2.
__global__ __launch_bounds__(256) void k_score(
    const float* __restrict__ tgt, const float* __restrict__ src,
    const int* __restrict__ lens, float* __restrict__ align_out) {
  const int j    = blockIdx.x;
  const int xcd  = j & 7;
  const int seq  = j >> 3;
  const int b    = ((seq >> 6) << 3) | xcd;   // 4 batch-groups of 8
  const int tile = seq & 63;
  const int t0   = (tile >> 3) * TILE;
  const int s0   = (tile & 7) * TILE;
  const int len  = get_len(lens, b);
  if (s0 >= len) return;   // fully-masked tile: softmax writes the zeros

  __shared__ short aHi[TILE * LP], aLo[TILE * LP], bHi[TILE * LP], bLo[TILE * LP];

  const int tid  = threadIdx.x;
  const int lane = tid & 63;
  const int wid  = tid >> 6;
  const int wt   = wid >> 1, wsd = wid & 1;    // 2x2 waves, 64x64 each
  const int g    = lane >> 4, r16 = lane & 15;
  const int srow = tid >> 3, sc4 = tid & 7;

  f32x4 acc[4][4];
#pragma unroll
  for (int m = 0; m < 4; ++m)
#pragma unroll
    for (int n = 0; n < 4; ++n) acc[m][n] = (f32x4){0.f, 0.f, 0.f, 0.f};

  const float* tgtB = tgt + ((size_t)(b * TLEN + t0)) * DIM;
  const float* srcB = src + ((size_t)(b * SLEN + s0)) * DIM;

  float4v va[4], vb[4];
#pragma unroll
  for (int r = 0; r < 4; ++r) {   // prologue: prefetch k0 = 0
    const int row = srow + 32 * r;
    va[r] = *(const float4v*)(tgtB + (size_t)row * DIM + sc4 * 4);
    vb[r] = *(const float4v*)(srcB + (size_t)row * DIM + sc4 * 4);
  }

  for (int k0 = 0; k0 < DIM; k0 += 32) {
    // phase 1: convert current regs -> LDS (vmcnt wait on prefetch lands here)
#pragma unroll
    for (int r = 0; r < 4; ++r) {
      const int row = srow + 32 * r;
      u32x2 ah, al, bh, bl;
      ah[0] = packhi(va[r][0], va[r][1]); ah[1] = packhi(va[r][2], va[r][3]);
      bh[0] = packhi(vb[r][0], vb[r][1]); bh[1] = packhi(vb[r][2], vb[r][3]);
      float ra0 = va[r][0] - fval(fbits(va[r][0]) & 0xFFFF0000u);
      float ra1 = va[r][1] - fval(fbits(va[r][1]) & 0xFFFF0000u);
      float ra2 = va[r][2] - fval(fbits(va[r][2]) & 0xFFFF0000u);
      float ra3 = va[r][3] - fval(fbits(va[r][3]) & 0xFFFF0000u);
      float rb0 = vb[r][0] - fval(fbits(vb[r][0]) & 0xFFFF0000u);
      float rb1 = vb[r][1] - fval(fbits(vb[r][1]) & 0xFFFF0000u);
      float rb2 = vb[r][2] - fval(fbits(vb[r][2]) & 0xFFFF0000u);
      float rb3 = vb[r][3] - fval(fbits(vb[r][3]) & 0xFFFF0000u);
      al[0] = packhi(ra0, ra1); al[1] = packhi(ra2, ra3);
      bl[0] = packhi(rb0, rb1); bl[1] = packhi(rb2, rb3);
      const int o = row * LP + sc4 * 4;
      *(u32x2*)(aHi + o) = ah; *(u32x2*)(aLo + o) = al;
      *(u32x2*)(bHi + o) = bh; *(u32x2*)(bLo + o) = bl;
    }
    // phase 2: issue next K-step loads (consumed after MFMA+barrier)
    if (k0 + 32 < DIM) {
#pragma unroll
      for (int r = 0; r < 4; ++r) {
        const int row = srow + 32 * r;
        va[r] = *(const float4v*)(tgtB + (size_t)row * DIM + (k0 + 32) + sc4 * 4);
        vb[r] = *(const float4v*)(srcB + (size_t)row * DIM + (k0 + 32) + sc4 * 4);
      }
    }
    __syncthreads();
    // phase 3: frags + MFMA (B hoisted, A per-m to limit VGPR peak)
    bf16x8 fbh[4], fbl[4];
#pragma unroll
    for (int n = 0; n < 4; ++n) {
      const int row = wsd * 64 + n * 16 + r16;
      fbh[n] = *(const bf16x8*)(bHi + row * LP + g * 8);
      fbl[n] = *(const bf16x8*)(bLo + row * LP + g * 8);
    }
#pragma unroll
    for (int m = 0; m < 4; ++m) {
      const int row = wt * 64 + m * 16 + r16;
      bf16x8 fah = *(const bf16x8*)(aHi + row * LP + g * 8);
      bf16x8 fal = *(const bf16x8*)(aLo + row * LP + g * 8);
#pragma unroll
      for (int n = 0; n < 4; ++n) {
        acc[m][n] = __builtin_amdgcn_mfma_f32_16x16x32_bf16(fah, fbh[n], acc[m][n], 0, 0, 0);
        acc[m][n] = __builtin_amdgcn_mfma_f32_16x16x32_bf16(fal, fbh[n], acc[m][n], 0, 0, 0);
        acc[m][n] = __builtin_amdgcn_mfma_f32_16x16x32_bf16(fah, fbl[n], acc[m][n], 0, 0, 0);
      }
    }
    __syncthreads();
  }
  float* outB = align_out + ((size_t)(b * TLEN + t0)) * SLEN + s0;
#pragma unroll
  for (int m = 0; m < 4; ++m) {
    const int tr = wt * 64 + m * 16 + g * 4;
#pragma unroll
    for (int n = 0; n < 4; ++n) {
      const int sc = wsd * 64 + n * 16 + r16;
#pragma unroll
      for (int r = 0; r < 4; ++r)
        outB[(size_t)(tr + r) * SLEN + sc] = acc[m][n][r];
    }
  }
}

// ---------------------------------------------------------------- K2: masked softmax (in-place)
__global__ __launch_bounds__(256) void k_softmax(
    const int* __restrict__ lens, float* __restrict__ align_io) {
  const int row  = blockIdx.x * 4 + (threadIdx.x >> 6);  // b*1024 + t
  const int lane = threadIdx.x & 63;
  const int b    = row >> 10;
  const int len  = get_len(lens, b);
  float* p = align_io + (size_t)row * SLEN;
  float v[4][4];
  float mx = -3.0e38f;
#pragma unroll
  for (int q = 0; q < 4; ++q) {
    if (256 * q >= len) {
#pragma unroll
      for (int j = 0; j < 4; ++j) v[q][j] = 0.f;
      continue;
    }
    const int sb = (lane + 64 * q) * 4;
    float4v x = *(const float4v*)(p + sb);
#pragma unroll
    for (int j = 0; j < 4; ++j) {
      v[q][j] = (sb + j < len) ? x[j] : 0.f;
      if (sb + j < len) mx = fmaxf(mx, x[j]);
    }
  }
#pragma unroll
  for (int off = 1; off < 64; off <<= 1) mx = fmaxf(mx, __shfl_xor(mx, off));
  float sum = 0.f;
#pragma unroll
  for (int q = 0; q < 4; ++q) {
    const int sb = (lane + 64 * q) * 4;
#pragma unroll
    for (int j = 0; j < 4; ++j) {
      float e = (sb + j < len) ? __expf(v[q][j] - mx) : 0.f;
      v[q][j] = e; sum += e;
    }
  }
#pragma unroll
  for (int off = 1; off < 64; off <<= 1) sum += __shfl_xor(sum, off);
  const float inv = 1.f / sum;
#pragma unroll
  for (int q = 0; q < 4; ++q) {
    float4v x;
#pragma unroll
    for (int j = 0; j < 4; ++j) x[j] = v[q][j] * inv;
    *(float4v*)(p + (lane + 64 * q) * 4) = x;
  }
}

// ---------------------------------------------------------------- K3: c = align @ src (bf16, K clamped, prefetch, XCD-pinned)
__global__ __launch_bounds__(256) void k_pv(
    const float* __restrict__ align_in, const unsigned short* __restrict__ srcT,
    const int* __restrict__ lens, unsigned short* __restrict__ cws) {
  const int j    = blockIdx.x;
  const int xcd  = j & 7;
  const int seq  = j >> 3;
  const int b    = ((seq >> 5) << 3) | xcd;   // 4 batch-groups of 8
  const int tile = seq & 31;
  const int t0   = (tile >> 2) * TILE;
  const int d0   = (tile & 3) * TILE;
  const int len = get_len(lens, b);
  const int ksteps = (len + 31) >> 5;

  __shared__ short A[TILE * LP], B[TILE * LP];
  const int tid  = threadIdx.x;
  const int lane = tid & 63;
  const int wid  = tid >> 6;
  const int wt   = wid >> 1, wsd = wid & 1;
  const int g    = lane >> 4, r16 = lane & 15;

  f32x4 acc[4][4];
#pragma unroll
  for (int m = 0; m < 4; ++m)
#pragma unroll
    for (int n = 0; n < 4; ++n) acc[m][n] = (f32x4){0.f, 0.f, 0.f, 0.f};

  const int arow = tid >> 3, ac4 = tid & 7;
  const int brow = tid >> 2, bc8 = tid & 3;

  float4v xa[4];
  bf16x8  xb[2];
#pragma unroll
  for (int r = 0; r < 4; ++r)
    xa[r] = *(const float4v*)(align_in + ((size_t)(b * TLEN + t0 + arow + 32 * r)) * SLEN + ac4 * 4);
#pragma unroll
  for (int r = 0; r < 2; ++r)
    xb[r] = *(const bf16x8*)(srcT + ((size_t)(b * DIM + d0 + brow + 64 * r)) * SLEN + bc8 * 8);

  for (int ks = 0; ks < ksteps; ++ks) {
#pragma unroll
    for (int r = 0; r < 4; ++r) {   // A: align rows t (trunc-bf16 ok: align in [0,1])
      u32x2 h;
      h[0] = packhi(xa[r][0], xa[r][1]); h[1] = packhi(xa[r][2], xa[r][3]);
      *(u32x2*)(A + (arow + 32 * r) * LP + ac4 * 4) = h;
    }
#pragma unroll
    for (int r = 0; r < 2; ++r)     // B: srcT rows d
      *(bf16x8*)(B + (brow + 64 * r) * LP + bc8 * 8) = xb[r];
    if (ks + 1 < ksteps) {
      const int k0 = (ks + 1) * 32;
#pragma unroll
      for (int r = 0; r < 4; ++r)
        xa[r] = *(const float4v*)(align_in + ((size_t)(b * TLEN + t0 + arow + 32 * r)) * SLEN + k0 + ac4 * 4);
#pragma unroll
      for (int r = 0; r < 2; ++r)
        xb[r] = *(const bf16x8*)(srcT + ((size_t)(b * DIM + d0 + brow + 64 * r)) * SLEN + k0 + bc8 * 8);
    }
    __syncthreads();
    bf16x8 fb[4];
#pragma unroll
    for (int n = 0; n < 4; ++n) fb[n] = *(const bf16x8*)(B + (wsd * 64 + n * 16 + r16) * LP + g * 8);
#pragma unroll
    for (int m = 0; m < 4; ++m) {
      bf16x8 fa = *(const bf16x8*)(A + (wt * 64 + m * 16 + r16) * LP + g * 8);
#pragma unroll
      for (int n = 0; n < 4; ++n)
        acc[m][n] = __builtin_amdgcn_mfma_f32_16x16x32_bf16(fa, fb[n], acc[m][n], 0, 0, 0);
    }
    __syncthreads();
  }
#pragma unroll
  for (int m = 0; m < 4; ++m) {
    const int tr = wt * 64 + m * 16 + g * 4;
#pragma unroll
    for (int n = 0; n < 4; ++n) {
      const int dc = wsd * 64 + n * 16 + r16;
#pragma unroll
      for (int r = 0; r < 4; ++r)
        cws[((size_t)(b * TLEN + t0 + tr + r)) * DIM + d0 + dc] = f2bf(acc[m][n][r]);
    }
  }
}

// ---------------------------------------------------------------- K4: attn_h = [c,tgt] @ w_out^T (bf16, XCD-pinned)
__global__ __launch_bounds__(256) void k_proj(
    const unsigned short* __restrict__ cws, const float* __restrict__ tgt,
    const unsigned short* __restrict__ wbf, float* __restrict__ attn_out) {
  const int j    = blockIdx.x;
  const int xcd  = j & 7;
  const int seq  = j >> 3;
  const int b    = ((seq >> 5) << 3) | xcd;
  const int tile = seq & 31;
  const int t0   = (tile >> 2) * TILE;
  const int d0   = (tile & 3) * TILE;

  __shared__ short A[TILE * LP], B[TILE * LP];
  const int tid  = threadIdx.x;
  const int lane = tid & 63;
  const int wid  = tid >> 6;
  const int wt   = wid >> 1, wsd = wid & 1;
  const int g    = lane >> 4, r16 = lane & 15;

  f32x4 acc[4][4];
#pragma unroll
  for (int m = 0; m < 4; ++m)
#pragma unroll
    for (int n = 0; n < 4; ++n) acc[m][n] = (f32x4){0.f, 0.f, 0.f, 0.f};

  for (int k0 = 0; k0 < 2 * DIM; k0 += 32) {
    if (k0 < DIM) {   // A from c (already bf16)
#pragma unroll
      for (int r = 0; r < 2; ++r) {
        const int row = (tid >> 2) + 64 * r, c8 = tid & 3;
        bf16x8 x = *(const bf16x8*)(cws + ((size_t)(b * TLEN + t0 + row)) * DIM + k0 + c8 * 8);
        *(bf16x8*)(A + row * LP + c8 * 8) = x;
      }
    } else {          // A from tgt (f32 -> bf16 RNE, margin for the fp32 output)
#pragma unroll
      for (int r = 0; r < 4; ++r) {
        const int row = (tid >> 3) + 32 * r, c4 = tid & 7;
        float4v x = *(const float4v*)(tgt + ((size_t)(b * TLEN + t0 + row)) * DIM + (k0 - DIM) + c4 * 4);
        bf16x4 h;
#pragma unroll
        for (int j2 = 0; j2 < 4; ++j2) h[j2] = (short)f2bf(x[j2]);
        *(bf16x4*)(A + row * LP + c4 * 4) = h;
      }
    }
#pragma unroll
    for (int r = 0; r < 2; ++r) {   // B: wbf rows d, cols e (bf16 copy)
      const int row = (tid >> 2) + 64 * r, c8 = tid & 3;
      bf16x8 x = *(const bf16x8*)(wbf + ((size_t)(d0 + row)) * (2 * DIM) + k0 + c8 * 8);
      *(bf16x8*)(B + row * LP + c8 * 8) = x;
    }
    __syncthreads();
    bf16x8 fb[4];
#pragma unroll
    for (int n = 0; n < 4; ++n) fb[n] = *(const bf16x8*)(B + (wsd * 64 + n * 16 + r16) * LP + g * 8);
#pragma unroll
    for (int m = 0; m < 4; ++m) {
      bf16x8 fa = *(const bf16x8*)(A + (wt * 64 + m * 16 + r16) * LP + g * 8);
#pragma unroll
      for (int n = 0; n < 4; ++n)
        acc[m][n] = __builtin_amdgcn_mfma_f32_16x16x32_bf16(fa, fb[n], acc[m][n], 0, 0, 0);
    }
    __syncthreads();
  }
#pragma unroll
  for (int m = 0; m < 4; ++m) {
    const int tr = wt * 64 + m * 16 + g * 4;
#pragma unroll
    for (int n = 0; n < 4; ++n) {
      const int dc = wsd * 64 + n * 16 + r16;
#pragma unroll
      for (int r = 0; r < 4; ++r)
        attn_out[((size_t)(b * TLEN + t0 + tr + r)) * DIM + d0 + dc] = acc[m][n][r];
    }
  }
}

extern "C" void kernel_launch(void* const* d_in, const int* in_sizes, int n_in,
                              void* d_out, int out_size, void* d_ws, size_t ws_size,
                              hipStream_t stream) {
  const float* src   = (const float*)d_in[0];
  const float* tgt   = (const float*)d_in[1];
  const int*   lens  = (const int*)d_in[2];
  const float* w_out = (const float*)d_in[3];

  float* attn_out  = (float*)d_out;                          // 32*1024*512 f32
  float* align_out = attn_out + (size_t)BZ * TLEN * DIM;     // 32*1024*1024 f32

  const size_t NE = (size_t)BZ * SLEN * DIM;
  const size_t NW = (size_t)DIM * 2 * DIM;
  unsigned short* srcT = (unsigned short*)d_ws;
  unsigned short* cws  = srcT + NE;
  unsigned short* wbf  = cws + NE;

  k_transpose<<<dim3(16, 8, BZ), 256, 0, stream>>>(src, srcT);
  k_prep_w<<<dim3((unsigned)(NW / 8 / 256)), 256, 0, stream>>>(w_out, wbf);
  k_score<<<dim3(2048), 256, 0, stream>>>(tgt, src, lens, align_out);
  k_softmax<<<dim3(BZ * TLEN / 4), 256, 0, stream>>>(lens, align_out);
  k_pv<<<dim3(1024), 256, 0, stream>>>(align_out, srcT, lens, cws);
  k_proj<<<dim3(1024), 256, 0, stream>>>(cws, tgt, wbf, attn_out);
}